// Round 11
// baseline (284.877 us; speedup 1.0000x reference)
//
#include <hip/hip_runtime.h>
#include <math.h>

// Problem constants (from reference)
constexpr int NN  = 100000;   // nodes
constexpr int EE  = 1600000;  // edges
constexpr int IND = 128;      // input dim
constexpr int HID = 64;       // hidden dim

constexpr int NBUCK = (NN + 127) / 128;   // 782 buckets of 128 nodes
constexpr int CAP   = 2432;               // bucket capacity (validated rounds 6-10)
constexpr int CHUNK = 4096;               // edges per multisplit block

// bf16 helpers
__device__ __forceinline__ unsigned short f2bf(float f) {
    union { float f; unsigned int u; } v; v.f = f;
    unsigned int r = (v.u + 0x7FFFu + ((v.u >> 16) & 1u)) >> 16;
    return (unsigned short)r;
}
// unpack a uint holding two bf16 (lo = bits 0..15, hi = bits 16..31)
__device__ __forceinline__ void unp(unsigned int u, float& lo, float& hi) {
    union { unsigned int x; float f; } a, c;
    a.x = u << 16; c.x = u & 0xFFFF0000u;
    lo = a.f; hi = c.f;
}

// accumulate 8 bf16 (one uint4) into a0..a7
#define ACC8(u) do { float l_, h_; \
    unp((u).x, l_, h_); a0 += l_; a1 += h_; \
    unp((u).y, l_, h_); a2 += l_; a3 += h_; \
    unp((u).z, l_, h_); a4 += l_; a5 += h_; \
    unp((u).w, l_, h_); a6 += l_; a7 += h_; } while (0)

// ---------------- small zero ----------------

__global__ __launch_bounds__(256) void k_zero(int* __restrict__ p, int n) {
    int i = blockIdx.x * 256 + threadIdx.x;
    if (i < n) p[i] = 0;
}

// ---------------- bucketized multisplit -------------------------------------

__global__ __launch_bounds__(256) void k_bscatter(const int* __restrict__ row, const int* __restrict__ col,
                                                  int* __restrict__ gcur, int* __restrict__ ebuf) {
    __shared__ int lhist[NBUCK];
    __shared__ int lbase[NBUCK];
    __shared__ int lcur[NBUCK];
    const int tx = threadIdx.x;
    const int cbase = blockIdx.x * CHUNK;

    for (int b = tx; b < NBUCK; b += 256) lhist[b] = 0;
    __syncthreads();

    #pragma unroll
    for (int i = 0; i < CHUNK / 256; ++i) {
        int e = cbase + tx + i * 256;
        if (e < EE) atomicAdd(&lhist[col[e] >> 7], 1);
    }
    __syncthreads();

    for (int b = tx; b < NBUCK; b += 256) {
        int c = lhist[b];
        if (c) lbase[b] = atomicAdd(&gcur[b], c);
        lcur[b] = 0;
    }
    __syncthreads();

    #pragma unroll
    for (int i = 0; i < CHUNK / 256; ++i) {
        int e = cbase + tx + i * 256;
        if (e < EE) {
            int c = col[e];
            int b = c >> 7;
            int rank = atomicAdd(&lcur[b], 1);
            ebuf[b * CAP + lbase[b] + rank] = (row[e] << 7) | (c & 127);
        }
    }
}

// ---------------- in-place per-bucket node sort -----------------------------

__global__ __launch_bounds__(256) void k_bsortip(const int* __restrict__ gcur, int* __restrict__ ebuf,
                                                 int* __restrict__ bc, float* __restrict__ dinv) {
    __shared__ int ebl[CAP];
    __shared__ int h[128];
    __shared__ int sc[128];
    __shared__ int cur[128];
    const int tx = threadIdx.x;
    const int b = blockIdx.x;
    const int cnt = gcur[b];
    int* eb = ebuf + b * CAP;

    if (tx < 128) h[tx] = 0;
    for (int e = tx; e < cnt; e += 256) ebl[e] = eb[e];
    __syncthreads();
    for (int e = tx; e < cnt; e += 256) atomicAdd(&h[ebl[e] & 127], 1);
    __syncthreads();

    if (tx < 128) sc[tx] = h[tx];
    __syncthreads();
    #pragma unroll
    for (int o = 1; o < 128; o <<= 1) {
        int add = (tx < 128 && tx >= o) ? sc[tx - o] : 0;
        __syncthreads();
        if (tx < 128) sc[tx] += add;
        __syncthreads();
    }
    if (tx < 128) {
        int ex = sc[tx] - h[tx];
        cur[tx] = ex;
        int g = b * 128 + tx;
        if (g < NN) {
            bc[g]   = (ex << 16) | h[tx];
            dinv[g] = rsqrtf((float)(h[tx] + 1));   // +1 = self-loop
        }
    }
    __syncthreads();

    for (int e = tx; e < cnt; e += 256) {
        int v = ebl[e];
        int r = atomicAdd(&cur[v & 127], 1);
        eb[r] = v >> 7;
    }
}

// ---------------- fc: h = x @ fc_w + fc_b  (128 -> 64), NO LDS --------------
// A from global (16-lane duplicate addresses merge in coalescer); B from
// global as one contiguous 256B segment per instr, L1-resident (w = 32 KB).
// No staging, no barrier, no DS ops -> removes the round-10 invariant.

__global__ __launch_bounds__(256) void k_fc(const float* __restrict__ x, const float* __restrict__ w,
                                            const float* __restrict__ b, float* __restrict__ h) {
    const int tx = threadIdx.x;
    const int tc = tx & 15;
    const int gr = tx >> 4;
    const int c0 = tc * 4;
    const int rbase = blockIdx.x * 64 + gr * 4;

    int o[4];
    #pragma unroll
    for (int i = 0; i < 4; ++i) {
        int rg = rbase + i;
        o[i] = (rg < NN ? rg : 0) * IND;
    }

    float4 bb = *(const float4*)&b[c0];
    float acc[4][4];
    #pragma unroll
    for (int i = 0; i < 4; ++i) {
        acc[i][0] = bb.x; acc[i][1] = bb.y; acc[i][2] = bb.z; acc[i][3] = bb.w;
    }

    #pragma unroll 2
    for (int kk = 0; kk < IND; kk += 4) {
        float4 a[4];
        #pragma unroll
        for (int i = 0; i < 4; ++i) a[i] = *(const float4*)(x + o[i] + kk);
        float4 b0 = *(const float4*)&w[(kk + 0) * HID + c0];
        float4 b1 = *(const float4*)&w[(kk + 1) * HID + c0];
        float4 b2 = *(const float4*)&w[(kk + 2) * HID + c0];
        float4 b3 = *(const float4*)&w[(kk + 3) * HID + c0];
        #pragma unroll
        for (int i = 0; i < 4; ++i) {
            acc[i][0] += a[i].x * b0.x + a[i].y * b1.x + a[i].z * b2.x + a[i].w * b3.x;
            acc[i][1] += a[i].x * b0.y + a[i].y * b1.y + a[i].z * b2.y + a[i].w * b3.y;
            acc[i][2] += a[i].x * b0.z + a[i].y * b1.z + a[i].z * b2.z + a[i].w * b3.z;
            acc[i][3] += a[i].x * b0.w + a[i].y * b1.w + a[i].z * b2.w + a[i].w * b3.w;
        }
    }

    #pragma unroll
    for (int i = 0; i < 4; ++i) {
        int rg = rbase + i;
        if (rg < NN)
            *(float4*)&h[rg * HID + c0] = make_float4(acc[i][0], acc[i][1], acc[i][2], acc[i][3]);
    }
}

// ---------------- conv transform: mdb = bf16((hin @ W) * dinv), NO LDS ------

__global__ __launch_bounds__(256) void k_mm(const float* __restrict__ hin, const float* __restrict__ w,
                                            const float* __restrict__ dinv,
                                            unsigned short* __restrict__ mdb) {
    const int tx = threadIdx.x;
    const int tc = tx & 15;
    const int gr = tx >> 4;
    const int c0 = tc * 4;
    const int rbase = blockIdx.x * 64 + gr * 4;

    int o[4];
    #pragma unroll
    for (int i = 0; i < 4; ++i) {
        int rg = rbase + i;
        o[i] = (rg < NN ? rg : 0) * HID;
    }

    float acc[4][4] = {};

    #pragma unroll 2
    for (int kk = 0; kk < HID; kk += 4) {
        float4 a[4];
        #pragma unroll
        for (int i = 0; i < 4; ++i) a[i] = *(const float4*)(hin + o[i] + kk);
        float4 b0 = *(const float4*)&w[(kk + 0) * HID + c0];
        float4 b1 = *(const float4*)&w[(kk + 1) * HID + c0];
        float4 b2 = *(const float4*)&w[(kk + 2) * HID + c0];
        float4 b3 = *(const float4*)&w[(kk + 3) * HID + c0];
        #pragma unroll
        for (int i = 0; i < 4; ++i) {
            acc[i][0] += a[i].x * b0.x + a[i].y * b1.x + a[i].z * b2.x + a[i].w * b3.x;
            acc[i][1] += a[i].x * b0.y + a[i].y * b1.y + a[i].z * b2.y + a[i].w * b3.y;
            acc[i][2] += a[i].x * b0.z + a[i].y * b1.z + a[i].z * b2.z + a[i].w * b3.z;
            acc[i][3] += a[i].x * b0.w + a[i].y * b1.w + a[i].z * b2.w + a[i].w * b3.w;
        }
    }

    #pragma unroll
    for (int i = 0; i < 4; ++i) {
        int rg = rbase + i;
        if (rg < NN) {
            float di = dinv[rg];
            ushort4 o4;
            o4.x = f2bf(acc[i][0] * di); o4.y = f2bf(acc[i][1] * di);
            o4.z = f2bf(acc[i][2] * di); o4.w = f2bf(acc[i][3] * di);
            *(ushort4*)&mdb[rg * HID + c0] = o4;
        }
    }
}

// ---------------- gather conv1: lane = (q=edge slot, f8=feature octet) ------
// 8 edges/pass, 8 bf16/lane via one uint4. Per 16 edges: 2 prow + 2 uint4
// VMEM instrs (vs 12 before). Butterfly merge across q (xor 8,16,32).

__global__ __launch_bounds__(256) void k_gather(const unsigned short* __restrict__ mdb,
                                                const int* __restrict__ prow, const int* __restrict__ bc,
                                                const float* __restrict__ dinv, const float* __restrict__ b,
                                                float* __restrict__ hout) {
    const uint4* md8 = (const uint4*)mdb;      // row = 8 uint4 (64 bf16)
    int lane = threadIdx.x & 63;
    int q  = lane >> 3;       // 0..7 edge slot
    int f8 = lane & 7;        // feature octet
    int wid  = (blockIdx.x * blockDim.x + threadIdx.x) >> 6;
    int nwv  = (gridDim.x * blockDim.x) >> 6;
    float4 bj0 = *(const float4*)&b[f8 * 8];
    float4 bj1 = *(const float4*)&b[f8 * 8 + 4];

    for (int i = wid; i < NN; i += nwv) {
        int vv = bc[i];
        int s = (i >> 7) * CAP + (vv >> 16);
        int n = vv & 0xFFFF;
        float a0 = 0.f, a1 = 0.f, a2 = 0.f, a3 = 0.f;
        float a4 = 0.f, a5 = 0.f, a6 = 0.f, a7 = 0.f;
        if (q == 0) {                      // self-loop term, counted once
            uint4 u = md8[i * 8 + f8];
            ACC8(u);
        }
        int e = 0;
        for (; e + 16 <= n; e += 16) {
            int r0 = prow[s + e + q];
            int r1 = prow[s + e + 8 + q];
            uint4 u0 = md8[r0 * 8 + f8];
            uint4 u1 = md8[r1 * 8 + f8];
            ACC8(u0); ACC8(u1);
        }
        if (e + 8 <= n) {
            int r0 = prow[s + e + q];
            uint4 u0 = md8[r0 * 8 + f8];
            ACC8(u0);
            e += 8;
        }
        if (e < n) {                       // guarded tail (<8 edges)
            int ej = e + q;
            int r = prow[s + (ej < n ? ej : 0)];
            uint4 u = md8[r * 8 + f8];
            if (ej < n) ACC8(u);
        }
        // butterfly merge across the 8 q-groups
        #pragma unroll
        for (int off = 8; off <= 32; off <<= 1) {
            a0 += __shfl_xor(a0, off, 64); a1 += __shfl_xor(a1, off, 64);
            a2 += __shfl_xor(a2, off, 64); a3 += __shfl_xor(a3, off, 64);
            a4 += __shfl_xor(a4, off, 64); a5 += __shfl_xor(a5, off, 64);
            a6 += __shfl_xor(a6, off, 64); a7 += __shfl_xor(a7, off, 64);
        }

        if (q == 0) {
            float di = dinv[i];
            float4 o0, o1;
            o0.x = fmaxf(di * a0 + bj0.x, 0.f); o0.y = fmaxf(di * a1 + bj0.y, 0.f);
            o0.z = fmaxf(di * a2 + bj0.z, 0.f); o0.w = fmaxf(di * a3 + bj0.w, 0.f);
            o1.x = fmaxf(di * a4 + bj1.x, 0.f); o1.y = fmaxf(di * a5 + bj1.y, 0.f);
            o1.z = fmaxf(di * a6 + bj1.z, 0.f); o1.w = fmaxf(di * a7 + bj1.w, 0.f);
            *(float4*)&hout[i * HID + f8 * 8]     = o0;
            *(float4*)&hout[i * HID + f8 * 8 + 4] = o1;
        }
    }
}

// ---------------- gather conv2 fused with scores ----------------------------

__global__ __launch_bounds__(256) void k_gather2s(const unsigned short* __restrict__ mdb,
        const int* __restrict__ prow, const int* __restrict__ bc, const float* __restrict__ dinv,
        const float* __restrict__ b, const float* __restrict__ nw, const float* __restrict__ nb,
        const float* __restrict__ ew, float* __restrict__ out_node,
        float* __restrict__ ssrc, float* __restrict__ sdst) {
    const uint4* md8 = (const uint4*)mdb;
    int lane = threadIdx.x & 63;
    int q  = lane >> 3;
    int f8 = lane & 7;
    int wid  = (blockIdx.x * blockDim.x + threadIdx.x) >> 6;
    int nwv  = (gridDim.x * blockDim.x) >> 6;
    float4 bj0 = *(const float4*)&b[f8 * 8];
    float4 bj1 = *(const float4*)&b[f8 * 8 + 4];
    float4 wn0 = *(const float4*)&nw[f8 * 8];
    float4 wn1 = *(const float4*)&nw[f8 * 8 + 4];
    float4 w10 = *(const float4*)&ew[f8 * 8];
    float4 w11 = *(const float4*)&ew[f8 * 8 + 4];
    float4 w20 = *(const float4*)&ew[64 + f8 * 8];
    float4 w21 = *(const float4*)&ew[64 + f8 * 8 + 4];
    float nb0 = nb[0];

    for (int i = wid; i < NN; i += nwv) {
        int vv = bc[i];
        int s = (i >> 7) * CAP + (vv >> 16);
        int n = vv & 0xFFFF;
        float a0 = 0.f, a1 = 0.f, a2 = 0.f, a3 = 0.f;
        float a4 = 0.f, a5 = 0.f, a6 = 0.f, a7 = 0.f;
        if (q == 0) {
            uint4 u = md8[i * 8 + f8];
            ACC8(u);
        }
        int e = 0;
        for (; e + 16 <= n; e += 16) {
            int r0 = prow[s + e + q];
            int r1 = prow[s + e + 8 + q];
            uint4 u0 = md8[r0 * 8 + f8];
            uint4 u1 = md8[r1 * 8 + f8];
            ACC8(u0); ACC8(u1);
        }
        if (e + 8 <= n) {
            int r0 = prow[s + e + q];
            uint4 u0 = md8[r0 * 8 + f8];
            ACC8(u0);
            e += 8;
        }
        if (e < n) {
            int ej = e + q;
            int r = prow[s + (ej < n ? ej : 0)];
            uint4 u = md8[r * 8 + f8];
            if (ej < n) ACC8(u);
        }
        #pragma unroll
        for (int off = 8; off <= 32; off <<= 1) {
            a0 += __shfl_xor(a0, off, 64); a1 += __shfl_xor(a1, off, 64);
            a2 += __shfl_xor(a2, off, 64); a3 += __shfl_xor(a3, off, 64);
            a4 += __shfl_xor(a4, off, 64); a5 += __shfl_xor(a5, off, 64);
            a6 += __shfl_xor(a6, off, 64); a7 += __shfl_xor(a7, off, 64);
        }

        float di = dinv[i];
        float v0 = fmaxf(di * a0 + bj0.x, 0.f), v1 = fmaxf(di * a1 + bj0.y, 0.f);
        float v2 = fmaxf(di * a2 + bj0.z, 0.f), v3 = fmaxf(di * a3 + bj0.w, 0.f);
        float v4 = fmaxf(di * a4 + bj1.x, 0.f), v5 = fmaxf(di * a5 + bj1.y, 0.f);
        float v6 = fmaxf(di * a6 + bj1.z, 0.f), v7 = fmaxf(di * a7 + bj1.w, 0.f);

        float a  = v0 * wn0.x + v1 * wn0.y + v2 * wn0.z + v3 * wn0.w
                 + v4 * wn1.x + v5 * wn1.y + v6 * wn1.z + v7 * wn1.w;
        float s1 = v0 * w10.x + v1 * w10.y + v2 * w10.z + v3 * w10.w
                 + v4 * w11.x + v5 * w11.y + v6 * w11.z + v7 * w11.w;
        float s2 = v0 * w20.x + v1 * w20.y + v2 * w20.z + v3 * w20.w
                 + v4 * w21.x + v5 * w21.y + v6 * w21.z + v7 * w21.w;
        // reduce across the 8 f8-octets (lanes differing in bits 0..2)
        #pragma unroll
        for (int off = 4; off; off >>= 1) {
            a  += __shfl_xor(a,  off, 64);
            s1 += __shfl_xor(s1, off, 64);
            s2 += __shfl_xor(s2, off, 64);
        }
        if (lane == 0) {
            out_node[i] = 1.f / (1.f + expf(-(a + nb0)));
            ssrc[i] = s1;
            sdst[i] = s2;
        }
    }
}

// ---------------- edge scores (x4 vectorized) -------------------------------

__global__ __launch_bounds__(256) void k_edge(const int4* __restrict__ row4, const int4* __restrict__ col4,
                                              const float* __restrict__ ssrc, const float* __restrict__ sdst,
                                              const float* __restrict__ eb, float4* __restrict__ out4) {
    constexpr int NQ = EE / 4;
    int i = blockIdx.x * 256 + threadIdx.x;
    if (i >= NQ) return;
    float eb0 = eb[0];
    int4 r = row4[i], c = col4[i];
    float4 o;
    float z;
    z = ssrc[r.x] + sdst[c.x] + eb0; o.x = 1.f / (1.f + expf(-z));
    z = ssrc[r.y] + sdst[c.y] + eb0; o.y = 1.f / (1.f + expf(-z));
    z = ssrc[r.z] + sdst[c.z] + eb0; o.z = 1.f / (1.f + expf(-z));
    z = ssrc[r.w] + sdst[c.w] + eb0; o.w = 1.f / (1.f + expf(-z));
    out4[i] = o;
}

extern "C" void kernel_launch(void* const* d_in, const int* in_sizes, int n_in,
                              void* d_out, int out_size, void* d_ws, size_t ws_size,
                              hipStream_t stream) {
    const float* x    = (const float*)d_in[0];
    const int*   ei   = (const int*)d_in[1];
    const float* fc_w = (const float*)d_in[2];
    const float* fc_b = (const float*)d_in[3];
    const float* c1w  = (const float*)d_in[4];
    const float* c1b  = (const float*)d_in[5];
    const float* c2w  = (const float*)d_in[6];
    const float* c2b  = (const float*)d_in[7];
    const float* nw   = (const float*)d_in[8];
    const float* nb   = (const float*)d_in[9];
    const float* ew   = (const float*)d_in[10];
    const float* eb   = (const float*)d_in[11];
    const int* row = ei;        // edge_index[0]
    const int* col = ei + EE;   // edge_index[1]

    // workspace layout (4B units): ~47 MB total
    constexpr int NP = 100352;
    float* ws   = (float*)d_ws;
    float* dinv = ws;                               // NP
    int*   bc   = (int*)(ws + NP);                  // NP
    int*   gcur = (int*)(ws + 2 * NP);              // 1024
    int*   ebuf = (int*)(ws + 2 * NP + 1024);       // NBUCK*CAP
    float* A    = ws + 2 * NP + 1024 + NBUCK * CAP; // h [N*HID] f32
    unsigned short* Bbf = (unsigned short*)(A + (size_t)NN * HID);  // md bf16 (16B-aligned)
    float* ssrc = A;                                // alias: A dead after 2nd k_mm
    float* sdst = A + NP;

    float* out_edge = (float*)d_out;
    float* out_node = out_edge + EE;

    const int nbG = (NN + 63) / 64;             // 1563 GEMM tiles (64 rows each)
    const int nbC = (EE + CHUNK - 1) / CHUNK;   // 391 multisplit chunks
    const int nbQ = (EE / 4 + 255) / 256;       // 1563 edge-quad blocks

    // ---- bucketize + in-place node sort (builds CSR + dinv) ----
    k_zero    <<<(NBUCK + 255) / 256, 256, 0, stream>>>(gcur, NBUCK);
    k_bscatter<<<nbC, 256, 0, stream>>>(row, col, gcur, ebuf);
    k_bsortip <<<NBUCK, 256, 0, stream>>>(gcur, ebuf, bc, dinv);

    // ---- fc, conv1 transform, conv1 gather ----
    k_fc    <<<nbG, 256, 0, stream>>>(x, fc_w, fc_b, A);
    k_mm    <<<nbG, 256, 0, stream>>>(A, c1w, dinv, Bbf);
    k_gather<<<2048, 256, 0, stream>>>(Bbf, ebuf, bc, dinv, c1b, A);

    // ---- conv2 transform + gather fused with scores ----
    k_mm      <<<nbG, 256, 0, stream>>>(A, c2w, dinv, Bbf);
    k_gather2s<<<2048, 256, 0, stream>>>(Bbf, ebuf, bc, dinv, c2b,
                                         nw, nb, ew, out_node, ssrc, sdst);

    // ---- edge scores ----
    k_edge<<<nbQ, 256, 0, stream>>>((const int4*)row, (const int4*)col,
                                    ssrc, sdst, eb, (float4*)out_edge);
}

// Round 12
// 216.484 us; speedup vs baseline: 1.3159x; 1.3159x over previous
//
#include <hip/hip_runtime.h>
#include <math.h>

// Problem constants (from reference)
constexpr int NN  = 100000;   // nodes
constexpr int EE  = 1600000;  // edges
constexpr int IND = 128;      // input dim
constexpr int HID = 64;       // hidden dim

constexpr int NBUCK = (NN + 127) / 128;   // 782 buckets of 128 nodes
constexpr int CAP   = 2432;               // bucket capacity (validated rounds 6-11)
constexpr int CHUNK = 4096;               // edges per multisplit block

// bf16 helpers
__device__ __forceinline__ unsigned short f2bf(float f) {
    union { float f; unsigned int u; } v; v.f = f;
    unsigned int r = (v.u + 0x7FFFu + ((v.u >> 16) & 1u)) >> 16;
    return (unsigned short)r;
}
// unpack a uint holding two bf16 (lo = bits 0..15, hi = bits 16..31)
__device__ __forceinline__ void unp(unsigned int u, float& lo, float& hi) {
    union { unsigned int x; float f; } a, c;
    a.x = u << 16; c.x = u & 0xFFFF0000u;
    lo = a.f; hi = c.f;
}

// ---------------- small zero ----------------

__global__ __launch_bounds__(256) void k_zero(int* __restrict__ p, int n) {
    int i = blockIdx.x * 256 + threadIdx.x;
    if (i < n) p[i] = 0;
}

// ---------------- bucketized multisplit -------------------------------------

__global__ __launch_bounds__(256) void k_bscatter(const int* __restrict__ row, const int* __restrict__ col,
                                                  int* __restrict__ gcur, int* __restrict__ ebuf) {
    __shared__ int lhist[NBUCK];
    __shared__ int lbase[NBUCK];
    __shared__ int lcur[NBUCK];
    const int tx = threadIdx.x;
    const int cbase = blockIdx.x * CHUNK;

    for (int b = tx; b < NBUCK; b += 256) lhist[b] = 0;
    __syncthreads();

    #pragma unroll
    for (int i = 0; i < CHUNK / 256; ++i) {
        int e = cbase + tx + i * 256;
        if (e < EE) atomicAdd(&lhist[col[e] >> 7], 1);
    }
    __syncthreads();

    for (int b = tx; b < NBUCK; b += 256) {
        int c = lhist[b];
        if (c) lbase[b] = atomicAdd(&gcur[b], c);
        lcur[b] = 0;
    }
    __syncthreads();

    #pragma unroll
    for (int i = 0; i < CHUNK / 256; ++i) {
        int e = cbase + tx + i * 256;
        if (e < EE) {
            int c = col[e];
            int b = c >> 7;
            int rank = atomicAdd(&lcur[b], 1);
            ebuf[b * CAP + lbase[b] + rank] = (row[e] << 7) | (c & 127);
        }
    }
}

// ---------------- in-place per-bucket node sort -----------------------------

__global__ __launch_bounds__(256) void k_bsortip(const int* __restrict__ gcur, int* __restrict__ ebuf,
                                                 int* __restrict__ bc, float* __restrict__ dinv) {
    __shared__ int ebl[CAP];
    __shared__ int h[128];
    __shared__ int sc[128];
    __shared__ int cur[128];
    const int tx = threadIdx.x;
    const int b = blockIdx.x;
    const int cnt = gcur[b];
    int* eb = ebuf + b * CAP;

    if (tx < 128) h[tx] = 0;
    for (int e = tx; e < cnt; e += 256) ebl[e] = eb[e];
    __syncthreads();
    for (int e = tx; e < cnt; e += 256) atomicAdd(&h[ebl[e] & 127], 1);
    __syncthreads();

    if (tx < 128) sc[tx] = h[tx];
    __syncthreads();
    #pragma unroll
    for (int o = 1; o < 128; o <<= 1) {
        int add = (tx < 128 && tx >= o) ? sc[tx - o] : 0;
        __syncthreads();
        if (tx < 128) sc[tx] += add;
        __syncthreads();
    }
    if (tx < 128) {
        int ex = sc[tx] - h[tx];
        cur[tx] = ex;
        int g = b * 128 + tx;
        if (g < NN) {
            bc[g]   = (ex << 16) | h[tx];
            dinv[g] = rsqrtf((float)(h[tx] + 1));   // +1 = self-loop
        }
    }
    __syncthreads();

    for (int e = tx; e < cnt; e += 256) {
        int v = ebl[e];
        int r = atomicAdd(&cur[v & 127], 1);
        eb[r] = v >> 7;
    }
}

// ---------------- combined weight: Wc = fc_w @ W1, bvec = fc_b @ W1 ---------
// (x@fc_w + fc_b)@W1 == x@Wc + bvec : exact fusion, no nonlinearity between.
// 33 blocks: 0..31 compute Wc (256 elems each), 32 computes bvec.

__global__ __launch_bounds__(256) void k_wc(const float* __restrict__ wfc, const float* __restrict__ bfc,
                                            const float* __restrict__ w1,
                                            float* __restrict__ wc, float* __restrict__ bvec) {
    int b = blockIdx.x, tx = threadIdx.x;
    if (b < 32) {
        int idx = b * 256 + tx;          // 0..8191
        int r = idx >> 6, c = idx & 63;
        float acc = 0.f;
        #pragma unroll 8
        for (int k = 0; k < 64; ++k) acc += wfc[r * HID + k] * w1[k * HID + c];
        wc[idx] = acc;
    } else if (tx < 64) {
        float acc = 0.f;
        #pragma unroll 8
        for (int k = 0; k < 64; ++k) acc += bfc[k] * w1[k * HID + tx];
        bvec[tx] = acc;
    }
}

// ---------------- fused fc+conv1 transform: mdb = bf16((x@Wc + bvec)*dinv) --
// Round-10 k_fc structure (proven 48us): 64-row tile, LDS-staged weights,
// A from global with wave-duplicate addresses, unroll 2.

__global__ __launch_bounds__(256) void k_mmx(const float* __restrict__ x, const float* __restrict__ wc,
                                             const float* __restrict__ bvec, const float* __restrict__ dinv,
                                             unsigned short* __restrict__ mdb) {
    __shared__ float sw[IND * HID];     // 32 KB
    const int tx = threadIdx.x;
    for (int i = tx; i < IND * HID; i += 256) sw[i] = wc[i];

    const int tc = tx & 15;
    const int gr = tx >> 4;
    const int c0 = tc * 4;
    const int rbase = blockIdx.x * 64 + gr * 4;

    int o[4];
    #pragma unroll
    for (int i = 0; i < 4; ++i) {
        int rg = rbase + i;
        o[i] = (rg < NN ? rg : 0) * IND;
    }
    __syncthreads();

    float4 bb = *(const float4*)&bvec[c0];
    float acc[4][4];
    #pragma unroll
    for (int i = 0; i < 4; ++i) {
        acc[i][0] = bb.x; acc[i][1] = bb.y; acc[i][2] = bb.z; acc[i][3] = bb.w;
    }

    #pragma unroll 2
    for (int kk = 0; kk < IND; kk += 4) {
        float4 a[4];
        #pragma unroll
        for (int i = 0; i < 4; ++i) a[i] = *(const float4*)(x + o[i] + kk);
        float4 b0 = *(const float4*)&sw[(kk + 0) * HID + c0];
        float4 b1 = *(const float4*)&sw[(kk + 1) * HID + c0];
        float4 b2 = *(const float4*)&sw[(kk + 2) * HID + c0];
        float4 b3 = *(const float4*)&sw[(kk + 3) * HID + c0];
        #pragma unroll
        for (int i = 0; i < 4; ++i) {
            acc[i][0] += a[i].x * b0.x + a[i].y * b1.x + a[i].z * b2.x + a[i].w * b3.x;
            acc[i][1] += a[i].x * b0.y + a[i].y * b1.y + a[i].z * b2.y + a[i].w * b3.y;
            acc[i][2] += a[i].x * b0.z + a[i].y * b1.z + a[i].z * b2.z + a[i].w * b3.z;
            acc[i][3] += a[i].x * b0.w + a[i].y * b1.w + a[i].z * b2.w + a[i].w * b3.w;
        }
    }

    #pragma unroll
    for (int i = 0; i < 4; ++i) {
        int rg = rbase + i;
        if (rg < NN) {
            float di = dinv[rg];
            ushort4 o4;
            o4.x = f2bf(acc[i][0] * di); o4.y = f2bf(acc[i][1] * di);
            o4.z = f2bf(acc[i][2] * di); o4.w = f2bf(acc[i][3] * di);
            *(ushort4*)&mdb[rg * HID + c0] = o4;
        }
    }
}

// ---------------- conv2 transform: mdb = bf16((h1 @ W2) * dinv) -------------
// Round-10 structure: 64-row tiles, 16 KB LDS, unroll 2.

__global__ __launch_bounds__(256) void k_mm(const float* __restrict__ hin, const float* __restrict__ w,
                                            const float* __restrict__ dinv,
                                            unsigned short* __restrict__ mdb) {
    __shared__ float sw[HID * HID];     // 16 KB
    const int tx = threadIdx.x;
    for (int i = tx; i < HID * HID; i += 256) sw[i] = w[i];

    const int tc = tx & 15;
    const int gr = tx >> 4;
    const int c0 = tc * 4;
    const int rbase = blockIdx.x * 64 + gr * 4;

    int o[4];
    #pragma unroll
    for (int i = 0; i < 4; ++i) {
        int rg = rbase + i;
        o[i] = (rg < NN ? rg : 0) * HID;
    }
    __syncthreads();

    float acc[4][4] = {};

    #pragma unroll 2
    for (int kk = 0; kk < HID; kk += 4) {
        float4 a[4];
        #pragma unroll
        for (int i = 0; i < 4; ++i) a[i] = *(const float4*)(hin + o[i] + kk);
        float4 b0 = *(const float4*)&sw[(kk + 0) * HID + c0];
        float4 b1 = *(const float4*)&sw[(kk + 1) * HID + c0];
        float4 b2 = *(const float4*)&sw[(kk + 2) * HID + c0];
        float4 b3 = *(const float4*)&sw[(kk + 3) * HID + c0];
        #pragma unroll
        for (int i = 0; i < 4; ++i) {
            acc[i][0] += a[i].x * b0.x + a[i].y * b1.x + a[i].z * b2.x + a[i].w * b3.x;
            acc[i][1] += a[i].x * b0.y + a[i].y * b1.y + a[i].z * b2.y + a[i].w * b3.y;
            acc[i][2] += a[i].x * b0.z + a[i].y * b1.z + a[i].z * b2.z + a[i].w * b3.z;
            acc[i][3] += a[i].x * b0.w + a[i].y * b1.w + a[i].z * b2.w + a[i].w * b3.w;
        }
    }

    #pragma unroll
    for (int i = 0; i < 4; ++i) {
        int rg = rbase + i;
        if (rg < NN) {
            float di = dinv[rg];
            ushort4 o4;
            o4.x = f2bf(acc[i][0] * di); o4.y = f2bf(acc[i][1] * di);
            o4.z = f2bf(acc[i][2] * di); o4.w = f2bf(acc[i][3] * di);
            *(ushort4*)&mdb[rg * HID + c0] = o4;
        }
    }
}

// ---------------- gather conv1 (round-10 proven): lane = (q, f4) ------------

__global__ __launch_bounds__(256) void k_gather(const unsigned short* __restrict__ mdb,
                                                const int* __restrict__ prow, const int* __restrict__ bc,
                                                const float* __restrict__ dinv, const float* __restrict__ b,
                                                float* __restrict__ hout) {
    const uint2* mdq = (const uint2*)mdb;      // 4 bf16 per element
    int lane = threadIdx.x & 63;
    int q    = lane >> 4;
    int f4   = lane & 15;
    int wid  = (blockIdx.x * blockDim.x + threadIdx.x) >> 6;
    int nwv  = (gridDim.x * blockDim.x) >> 6;
    float4 bj = *(const float4*)&b[f4 * 4];

    for (int i = wid; i < NN; i += nwv) {
        int vv = bc[i];
        int s = (i >> 7) * CAP + (vv >> 16);
        int n = vv & 0xFFFF;
        float a0 = 0.f, a1 = 0.f, a2 = 0.f, a3 = 0.f;
        if (q == 0) {                      // self-loop term, counted once
            uint2 u = mdq[i * 16 + f4];
            float l, h_;
            unp(u.x, l, h_); a0 += l; a1 += h_;
            unp(u.y, l, h_); a2 += l; a3 += h_;
        }
        int e = 0;
        for (; e + 8 <= n; e += 8) {       // 8 edges per iteration, unguarded
            int r0 = prow[s + e + q];
            int r1 = prow[s + e + 4 + q];
            uint2 u0 = mdq[r0 * 16 + f4];
            uint2 u1 = mdq[r1 * 16 + f4];
            float l, h_;
            unp(u0.x, l, h_); a0 += l; a1 += h_;
            unp(u0.y, l, h_); a2 += l; a3 += h_;
            unp(u1.x, l, h_); a0 += l; a1 += h_;
            unp(u1.y, l, h_); a2 += l; a3 += h_;
        }
        for (; e < n; e += 4) {            // guarded tail (<= 2 iterations)
            int ej = e + q;
            int r = prow[s + (ej < n ? ej : 0)];
            uint2 u = mdq[r * 16 + f4];
            if (ej < n) {
                float l, h_;
                unp(u.x, l, h_); a0 += l; a1 += h_;
                unp(u.y, l, h_); a2 += l; a3 += h_;
            }
        }
        // merge quarters
        a0 += __shfl_xor(a0, 32, 64); a1 += __shfl_xor(a1, 32, 64);
        a2 += __shfl_xor(a2, 32, 64); a3 += __shfl_xor(a3, 32, 64);
        a0 += __shfl_xor(a0, 16, 64); a1 += __shfl_xor(a1, 16, 64);
        a2 += __shfl_xor(a2, 16, 64); a3 += __shfl_xor(a3, 16, 64);

        float di = dinv[i];
        float4 o;
        o.x = fmaxf(di * a0 + bj.x, 0.f);
        o.y = fmaxf(di * a1 + bj.y, 0.f);
        o.z = fmaxf(di * a2 + bj.z, 0.f);
        o.w = fmaxf(di * a3 + bj.w, 0.f);
        if (q == 0) *(float4*)&hout[i * HID + f4 * 4] = o;
    }
}

// ---------------- gather conv2 fused with scores (round-10 proven) ----------

__global__ __launch_bounds__(256) void k_gather2s(const unsigned short* __restrict__ mdb,
        const int* __restrict__ prow, const int* __restrict__ bc, const float* __restrict__ dinv,
        const float* __restrict__ b, const float* __restrict__ nw, const float* __restrict__ nb,
        const float* __restrict__ ew, float* __restrict__ out_node,
        float* __restrict__ ssrc, float* __restrict__ sdst) {
    const uint2* mdq = (const uint2*)mdb;
    int lane = threadIdx.x & 63;
    int q    = lane >> 4;
    int f4   = lane & 15;
    int wid  = (blockIdx.x * blockDim.x + threadIdx.x) >> 6;
    int nwv  = (gridDim.x * blockDim.x) >> 6;
    float4 bj  = *(const float4*)&b[f4 * 4];
    float4 wn  = *(const float4*)&nw[f4 * 4];
    float4 we1 = *(const float4*)&ew[f4 * 4];
    float4 we2 = *(const float4*)&ew[64 + f4 * 4];
    float nb0 = nb[0];

    for (int i = wid; i < NN; i += nwv) {
        int vv = bc[i];
        int s = (i >> 7) * CAP + (vv >> 16);
        int n = vv & 0xFFFF;
        float a0 = 0.f, a1 = 0.f, a2 = 0.f, a3 = 0.f;
        if (q == 0) {
            uint2 u = mdq[i * 16 + f4];
            float l, h_;
            unp(u.x, l, h_); a0 += l; a1 += h_;
            unp(u.y, l, h_); a2 += l; a3 += h_;
        }
        int e = 0;
        for (; e + 8 <= n; e += 8) {
            int r0 = prow[s + e + q];
            int r1 = prow[s + e + 4 + q];
            uint2 u0 = mdq[r0 * 16 + f4];
            uint2 u1 = mdq[r1 * 16 + f4];
            float l, h_;
            unp(u0.x, l, h_); a0 += l; a1 += h_;
            unp(u0.y, l, h_); a2 += l; a3 += h_;
            unp(u1.x, l, h_); a0 += l; a1 += h_;
            unp(u1.y, l, h_); a2 += l; a3 += h_;
        }
        for (; e < n; e += 4) {
            int ej = e + q;
            int r = prow[s + (ej < n ? ej : 0)];
            uint2 u = mdq[r * 16 + f4];
            if (ej < n) {
                float l, h_;
                unp(u.x, l, h_); a0 += l; a1 += h_;
                unp(u.y, l, h_); a2 += l; a3 += h_;
            }
        }
        a0 += __shfl_xor(a0, 32, 64); a1 += __shfl_xor(a1, 32, 64);
        a2 += __shfl_xor(a2, 32, 64); a3 += __shfl_xor(a3, 32, 64);
        a0 += __shfl_xor(a0, 16, 64); a1 += __shfl_xor(a1, 16, 64);
        a2 += __shfl_xor(a2, 16, 64); a3 += __shfl_xor(a3, 16, 64);

        float di = dinv[i];
        float v0 = fmaxf(di * a0 + bj.x, 0.f);
        float v1 = fmaxf(di * a1 + bj.y, 0.f);
        float v2 = fmaxf(di * a2 + bj.z, 0.f);
        float v3 = fmaxf(di * a3 + bj.w, 0.f);

        float a  = v0 * wn.x  + v1 * wn.y  + v2 * wn.z  + v3 * wn.w;
        float s1 = v0 * we1.x + v1 * we1.y + v2 * we1.z + v3 * we1.w;
        float s2 = v0 * we2.x + v1 * we2.y + v2 * we2.z + v3 * we2.w;
        #pragma unroll
        for (int off = 8; off; off >>= 1) {
            a  += __shfl_xor(a,  off, 64);
            s1 += __shfl_xor(s1, off, 64);
            s2 += __shfl_xor(s2, off, 64);
        }
        if (lane == 0) {
            out_node[i] = 1.f / (1.f + expf(-(a + nb0)));
            ssrc[i] = s1;
            sdst[i] = s2;
        }
    }
}

// ---------------- edge scores (x4 vectorized) -------------------------------

__global__ __launch_bounds__(256) void k_edge(const int4* __restrict__ row4, const int4* __restrict__ col4,
                                              const float* __restrict__ ssrc, const float* __restrict__ sdst,
                                              const float* __restrict__ eb, float4* __restrict__ out4) {
    constexpr int NQ = EE / 4;
    int i = blockIdx.x * 256 + threadIdx.x;
    if (i >= NQ) return;
    float eb0 = eb[0];
    int4 r = row4[i], c = col4[i];
    float4 o;
    float z;
    z = ssrc[r.x] + sdst[c.x] + eb0; o.x = 1.f / (1.f + expf(-z));
    z = ssrc[r.y] + sdst[c.y] + eb0; o.y = 1.f / (1.f + expf(-z));
    z = ssrc[r.z] + sdst[c.z] + eb0; o.z = 1.f / (1.f + expf(-z));
    z = ssrc[r.w] + sdst[c.w] + eb0; o.w = 1.f / (1.f + expf(-z));
    out4[i] = o;
}

extern "C" void kernel_launch(void* const* d_in, const int* in_sizes, int n_in,
                              void* d_out, int out_size, void* d_ws, size_t ws_size,
                              hipStream_t stream) {
    const float* x    = (const float*)d_in[0];
    const int*   ei   = (const int*)d_in[1];
    const float* fc_w = (const float*)d_in[2];
    const float* fc_b = (const float*)d_in[3];
    const float* c1w  = (const float*)d_in[4];
    const float* c1b  = (const float*)d_in[5];
    const float* c2w  = (const float*)d_in[6];
    const float* c2b  = (const float*)d_in[7];
    const float* nw   = (const float*)d_in[8];
    const float* nb   = (const float*)d_in[9];
    const float* ew   = (const float*)d_in[10];
    const float* eb   = (const float*)d_in[11];
    const int* row = ei;        // edge_index[0]
    const int* col = ei + EE;   // edge_index[1]

    // workspace layout (4B units): ~47 MB total
    constexpr int NP = 100352;
    float* ws   = (float*)d_ws;
    float* dinv = ws;                               // NP
    int*   bc   = (int*)(ws + NP);                  // NP
    int*   gcur = (int*)(ws + 2 * NP);              // 1024
    float* wc   = ws + 2 * NP + 1024;               // 8192 (fc_w @ W1)
    float* bvec = wc + 8192;                        // 64 (+pad to 128)
    int*   ebuf = (int*)(bvec + 128);               // NBUCK*CAP
    float* A    = (float*)(ebuf + NBUCK * CAP);     // h1 [N*HID] f32
    unsigned short* Bbf = (unsigned short*)(A + (size_t)NN * HID);  // md bf16
    float* ssrc = A;                                // alias: A dead after k_mm(conv2)
    float* sdst = A + NP;

    float* out_edge = (float*)d_out;
    float* out_node = out_edge + EE;

    const int nbG = (NN + 63) / 64;             // 1563 GEMM tiles (64 rows each)
    const int nbC = (EE + CHUNK - 1) / CHUNK;   // 391 multisplit chunks
    const int nbQ = (EE / 4 + 255) / 256;       // 1563 edge-quad blocks

    // ---- bucketize + in-place node sort (builds CSR + dinv) ----
    k_zero    <<<(NBUCK + 255) / 256, 256, 0, stream>>>(gcur, NBUCK);
    k_bscatter<<<nbC, 256, 0, stream>>>(row, col, gcur, ebuf);
    k_bsortip <<<NBUCK, 256, 0, stream>>>(gcur, ebuf, bc, dinv);

    // ---- combined fc+conv1 weights, fused transform, conv1 gather ----
    k_wc    <<<33, 256, 0, stream>>>(fc_w, fc_b, c1w, wc, bvec);
    k_mmx   <<<nbG, 256, 0, stream>>>(x, wc, bvec, dinv, Bbf);
    k_gather<<<2048, 256, 0, stream>>>(Bbf, ebuf, bc, dinv, c1b, A);

    // ---- conv2 transform + gather fused with scores ----
    k_mm      <<<nbG, 256, 0, stream>>>(A, c2w, dinv, Bbf);
    k_gather2s<<<2048, 256, 0, stream>>>(Bbf, ebuf, bc, dinv, c2b,
                                         nw, nb, ew, out_node, ssrc, sdst);

    // ---- edge scores ----
    k_edge<<<nbQ, 256, 0, stream>>>((const int4*)row, (const int4*)col,
                                    ssrc, sdst, eb, (float4*)out_edge);
}

// Round 13
// 214.154 us; speedup vs baseline: 1.3302x; 1.0109x over previous
//
#include <hip/hip_runtime.h>
#include <math.h>

// Problem constants (from reference)
constexpr int NN  = 100000;   // nodes
constexpr int EE  = 1600000;  // edges
constexpr int IND = 128;      // input dim
constexpr int HID = 64;       // hidden dim

constexpr int NBUCK = (NN + 127) / 128;   // 782 buckets of 128 nodes
constexpr int CAP   = 2432;               // bucket capacity (validated rounds 6-12)
constexpr int CHUNK = 4096;               // edges per multisplit block

// bf16 helpers
__device__ __forceinline__ unsigned short f2bf(float f) {
    union { float f; unsigned int u; } v; v.f = f;
    unsigned int r = (v.u + 0x7FFFu + ((v.u >> 16) & 1u)) >> 16;
    return (unsigned short)r;
}
// unpack a uint holding two bf16 (lo = bits 0..15, hi = bits 16..31)
__device__ __forceinline__ void unp(unsigned int u, float& lo, float& hi) {
    union { unsigned int x; float f; } a, c;
    a.x = u << 16; c.x = u & 0xFFFF0000u;
    lo = a.f; hi = c.f;
}

// accumulate one uint2 (4 bf16) into a0..a3
#define ACC4(u) do { float l_, h_; \
    unp((u).x, l_, h_); a0 += l_; a1 += h_; \
    unp((u).y, l_, h_); a2 += l_; a3 += h_; } while (0)

// ---------------- small zero ----------------

__global__ __launch_bounds__(256) void k_zero(int* __restrict__ p, int n) {
    int i = blockIdx.x * 256 + threadIdx.x;
    if (i < n) p[i] = 0;
}

// ---------------- bucketized multisplit -------------------------------------

__global__ __launch_bounds__(256) void k_bscatter(const int* __restrict__ row, const int* __restrict__ col,
                                                  int* __restrict__ gcur, int* __restrict__ ebuf) {
    __shared__ int lhist[NBUCK];
    __shared__ int lbase[NBUCK];
    __shared__ int lcur[NBUCK];
    const int tx = threadIdx.x;
    const int cbase = blockIdx.x * CHUNK;

    for (int b = tx; b < NBUCK; b += 256) lhist[b] = 0;
    __syncthreads();

    #pragma unroll
    for (int i = 0; i < CHUNK / 256; ++i) {
        int e = cbase + tx + i * 256;
        if (e < EE) atomicAdd(&lhist[col[e] >> 7], 1);
    }
    __syncthreads();

    for (int b = tx; b < NBUCK; b += 256) {
        int c = lhist[b];
        if (c) lbase[b] = atomicAdd(&gcur[b], c);
        lcur[b] = 0;
    }
    __syncthreads();

    #pragma unroll
    for (int i = 0; i < CHUNK / 256; ++i) {
        int e = cbase + tx + i * 256;
        if (e < EE) {
            int c = col[e];
            int b = c >> 7;
            int rank = atomicAdd(&lcur[b], 1);
            ebuf[b * CAP + lbase[b] + rank] = (row[e] << 7) | (c & 127);
        }
    }
}

// ---------------- in-place per-bucket node sort -----------------------------

__global__ __launch_bounds__(256) void k_bsortip(const int* __restrict__ gcur, int* __restrict__ ebuf,
                                                 int* __restrict__ bc, float* __restrict__ dinv) {
    __shared__ int ebl[CAP];
    __shared__ int h[128];
    __shared__ int sc[128];
    __shared__ int cur[128];
    const int tx = threadIdx.x;
    const int b = blockIdx.x;
    const int cnt = gcur[b];
    int* eb = ebuf + b * CAP;

    if (tx < 128) h[tx] = 0;
    for (int e = tx; e < cnt; e += 256) ebl[e] = eb[e];
    __syncthreads();
    for (int e = tx; e < cnt; e += 256) atomicAdd(&h[ebl[e] & 127], 1);
    __syncthreads();

    if (tx < 128) sc[tx] = h[tx];
    __syncthreads();
    #pragma unroll
    for (int o = 1; o < 128; o <<= 1) {
        int add = (tx < 128 && tx >= o) ? sc[tx - o] : 0;
        __syncthreads();
        if (tx < 128) sc[tx] += add;
        __syncthreads();
    }
    if (tx < 128) {
        int ex = sc[tx] - h[tx];
        cur[tx] = ex;
        int g = b * 128 + tx;
        if (g < NN) {
            bc[g]   = (ex << 16) | h[tx];
            dinv[g] = rsqrtf((float)(h[tx] + 1));   // +1 = self-loop
        }
    }
    __syncthreads();

    for (int e = tx; e < cnt; e += 256) {
        int v = ebl[e];
        int r = atomicAdd(&cur[v & 127], 1);
        eb[r] = v >> 7;
    }
}

// ---------------- combined weight: Wc = fc_w @ W1, bvec = fc_b @ W1 ---------

__global__ __launch_bounds__(256) void k_wc(const float* __restrict__ wfc, const float* __restrict__ bfc,
                                            const float* __restrict__ w1,
                                            float* __restrict__ wc, float* __restrict__ bvec) {
    int b = blockIdx.x, tx = threadIdx.x;
    if (b < 32) {
        int idx = b * 256 + tx;          // 0..8191
        int r = idx >> 6, c = idx & 63;
        float acc = 0.f;
        #pragma unroll 8
        for (int k = 0; k < 64; ++k) acc += wfc[r * HID + k] * w1[k * HID + c];
        wc[idx] = acc;
    } else if (tx < 64) {
        float acc = 0.f;
        #pragma unroll 8
        for (int k = 0; k < 64; ++k) acc += bfc[k] * w1[k * HID + tx];
        bvec[tx] = acc;
    }
}

// ---------------- fused fc+conv1 transform: mdb = bf16((x@Wc + bvec)*dinv) --
// Two-stage 16 KB weight staging (K halves): LDS cap rises 5 -> 8 blocks/CU
// (thread-capped), the isolated k_mm-vs-k_mmx occupancy difference.

__global__ __launch_bounds__(256) void k_mmx(const float* __restrict__ x, const float* __restrict__ wc,
                                             const float* __restrict__ bvec, const float* __restrict__ dinv,
                                             unsigned short* __restrict__ mdb) {
    __shared__ float sw[64 * HID];      // 16 KB (one K-half)
    const int tx = threadIdx.x;
    const int tc = tx & 15;
    const int gr = tx >> 4;
    const int c0 = tc * 4;
    const int rbase = blockIdx.x * 64 + gr * 4;

    int o[4];
    #pragma unroll
    for (int i = 0; i < 4; ++i) {
        int rg = rbase + i;
        o[i] = (rg < NN ? rg : 0) * IND;
    }

    float4 bb = *(const float4*)&bvec[c0];
    float acc[4][4];
    #pragma unroll
    for (int i = 0; i < 4; ++i) {
        acc[i][0] = bb.x; acc[i][1] = bb.y; acc[i][2] = bb.z; acc[i][3] = bb.w;
    }

    #pragma unroll 1
    for (int half = 0; half < 2; ++half) {
        __syncthreads();   // protect prior half's reads
        for (int i = tx; i < 64 * HID; i += 256) sw[i] = wc[half * 64 * HID + i];
        __syncthreads();
        const int kb = half * 64;
        #pragma unroll 2
        for (int kk = 0; kk < 64; kk += 4) {
            float4 a[4];
            #pragma unroll
            for (int i = 0; i < 4; ++i) a[i] = *(const float4*)(x + o[i] + kb + kk);
            float4 b0 = *(const float4*)&sw[(kk + 0) * HID + c0];
            float4 b1 = *(const float4*)&sw[(kk + 1) * HID + c0];
            float4 b2 = *(const float4*)&sw[(kk + 2) * HID + c0];
            float4 b3 = *(const float4*)&sw[(kk + 3) * HID + c0];
            #pragma unroll
            for (int i = 0; i < 4; ++i) {
                acc[i][0] += a[i].x * b0.x + a[i].y * b1.x + a[i].z * b2.x + a[i].w * b3.x;
                acc[i][1] += a[i].x * b0.y + a[i].y * b1.y + a[i].z * b2.y + a[i].w * b3.y;
                acc[i][2] += a[i].x * b0.z + a[i].y * b1.z + a[i].z * b2.z + a[i].w * b3.z;
                acc[i][3] += a[i].x * b0.w + a[i].y * b1.w + a[i].z * b2.w + a[i].w * b3.w;
            }
        }
    }

    #pragma unroll
    for (int i = 0; i < 4; ++i) {
        int rg = rbase + i;
        if (rg < NN) {
            float di = dinv[rg];
            ushort4 o4;
            o4.x = f2bf(acc[i][0] * di); o4.y = f2bf(acc[i][1] * di);
            o4.z = f2bf(acc[i][2] * di); o4.w = f2bf(acc[i][3] * di);
            *(ushort4*)&mdb[rg * HID + c0] = o4;
        }
    }
}

// ---------------- conv2 transform: mdb = bf16((h1 @ W2) * dinv) -------------

__global__ __launch_bounds__(256) void k_mm(const float* __restrict__ hin, const float* __restrict__ w,
                                            const float* __restrict__ dinv,
                                            unsigned short* __restrict__ mdb) {
    __shared__ float sw[HID * HID];     // 16 KB
    const int tx = threadIdx.x;
    for (int i = tx; i < HID * HID; i += 256) sw[i] = w[i];

    const int tc = tx & 15;
    const int gr = tx >> 4;
    const int c0 = tc * 4;
    const int rbase = blockIdx.x * 64 + gr * 4;

    int o[4];
    #pragma unroll
    for (int i = 0; i < 4; ++i) {
        int rg = rbase + i;
        o[i] = (rg < NN ? rg : 0) * HID;
    }
    __syncthreads();

    float acc[4][4] = {};

    #pragma unroll 2
    for (int kk = 0; kk < HID; kk += 4) {
        float4 a[4];
        #pragma unroll
        for (int i = 0; i < 4; ++i) a[i] = *(const float4*)(hin + o[i] + kk);
        float4 b0 = *(const float4*)&sw[(kk + 0) * HID + c0];
        float4 b1 = *(const float4*)&sw[(kk + 1) * HID + c0];
        float4 b2 = *(const float4*)&sw[(kk + 2) * HID + c0];
        float4 b3 = *(const float4*)&sw[(kk + 3) * HID + c0];
        #pragma unroll
        for (int i = 0; i < 4; ++i) {
            acc[i][0] += a[i].x * b0.x + a[i].y * b1.x + a[i].z * b2.x + a[i].w * b3.x;
            acc[i][1] += a[i].x * b0.y + a[i].y * b1.y + a[i].z * b2.y + a[i].w * b3.y;
            acc[i][2] += a[i].x * b0.z + a[i].y * b1.z + a[i].z * b2.z + a[i].w * b3.z;
            acc[i][3] += a[i].x * b0.w + a[i].y * b1.w + a[i].z * b2.w + a[i].w * b3.w;
        }
    }

    #pragma unroll
    for (int i = 0; i < 4; ++i) {
        int rg = rbase + i;
        if (rg < NN) {
            float di = dinv[rg];
            ushort4 o4;
            o4.x = f2bf(acc[i][0] * di); o4.y = f2bf(acc[i][1] * di);
            o4.z = f2bf(acc[i][2] * di); o4.w = f2bf(acc[i][3] * di);
            *(ushort4*)&mdb[rg * HID + c0] = o4;
        }
    }
}

// ---------------- gather conv1: 16-edge masked passes, 4 chains deep --------
// lane = (q=lane>>4, f4=lane&15). Per pass: 4 independent prow loads, then
// 4 independent md loads (double the MLP of the 8-edge version), OOR slots
// clamped to a valid address and zeroed (bf16 0 == 0.0f) before accumulate.
// No tail loop: ~22% of edges no longer fall into a guarded serial tail.

__global__ __launch_bounds__(256) void k_gather(const unsigned short* __restrict__ mdb,
                                                const int* __restrict__ prow, const int* __restrict__ bc,
                                                const float* __restrict__ dinv, const float* __restrict__ b,
                                                float* __restrict__ hout) {
    const uint2* mdq = (const uint2*)mdb;      // 4 bf16 per element
    int lane = threadIdx.x & 63;
    int q    = lane >> 4;
    int f4   = lane & 15;
    int wid  = (blockIdx.x * blockDim.x + threadIdx.x) >> 6;
    int nwv  = (gridDim.x * blockDim.x) >> 6;
    float4 bj = *(const float4*)&b[f4 * 4];

    for (int i = wid; i < NN; i += nwv) {
        int vv = bc[i];
        int s = (i >> 7) * CAP + (vv >> 16);
        int n = vv & 0xFFFF;
        float a0 = 0.f, a1 = 0.f, a2 = 0.f, a3 = 0.f;
        if (q == 0) {                      // self-loop term, counted once
            uint2 u = mdq[i * 16 + f4];
            ACC4(u);
        }
        for (int e = 0; e < n; e += 16) {
            int e0 = e + q, e1 = e + 4 + q, e2 = e + 8 + q, e3 = e + 12 + q;
            int r0 = prow[s + (e0 < n ? e0 : 0)];
            int r1 = prow[s + (e1 < n ? e1 : 0)];
            int r2 = prow[s + (e2 < n ? e2 : 0)];
            int r3 = prow[s + (e3 < n ? e3 : 0)];
            uint2 u0 = mdq[r0 * 16 + f4];
            uint2 u1 = mdq[r1 * 16 + f4];
            uint2 u2 = mdq[r2 * 16 + f4];
            uint2 u3 = mdq[r3 * 16 + f4];
            if (e1 >= n) { u1.x = 0u; u1.y = 0u; }
            if (e2 >= n) { u2.x = 0u; u2.y = 0u; }
            if (e3 >= n) { u3.x = 0u; u3.y = 0u; }
            if (e0 >= n) { u0.x = 0u; u0.y = 0u; }
            ACC4(u0); ACC4(u1); ACC4(u2); ACC4(u3);
        }
        // merge quarters
        a0 += __shfl_xor(a0, 32, 64); a1 += __shfl_xor(a1, 32, 64);
        a2 += __shfl_xor(a2, 32, 64); a3 += __shfl_xor(a3, 32, 64);
        a0 += __shfl_xor(a0, 16, 64); a1 += __shfl_xor(a1, 16, 64);
        a2 += __shfl_xor(a2, 16, 64); a3 += __shfl_xor(a3, 16, 64);

        float di = dinv[i];
        float4 o;
        o.x = fmaxf(di * a0 + bj.x, 0.f);
        o.y = fmaxf(di * a1 + bj.y, 0.f);
        o.z = fmaxf(di * a2 + bj.z, 0.f);
        o.w = fmaxf(di * a3 + bj.w, 0.f);
        if (q == 0) *(float4*)&hout[i * HID + f4 * 4] = o;
    }
}

// ---------------- gather conv2 fused with scores (same restructure) ---------

__global__ __launch_bounds__(256) void k_gather2s(const unsigned short* __restrict__ mdb,
        const int* __restrict__ prow, const int* __restrict__ bc, const float* __restrict__ dinv,
        const float* __restrict__ b, const float* __restrict__ nw, const float* __restrict__ nb,
        const float* __restrict__ ew, float* __restrict__ out_node,
        float* __restrict__ ssrc, float* __restrict__ sdst) {
    const uint2* mdq = (const uint2*)mdb;
    int lane = threadIdx.x & 63;
    int q    = lane >> 4;
    int f4   = lane & 15;
    int wid  = (blockIdx.x * blockDim.x + threadIdx.x) >> 6;
    int nwv  = (gridDim.x * blockDim.x) >> 6;
    float4 bj  = *(const float4*)&b[f4 * 4];
    float4 wn  = *(const float4*)&nw[f4 * 4];
    float4 we1 = *(const float4*)&ew[f4 * 4];
    float4 we2 = *(const float4*)&ew[64 + f4 * 4];
    float nb0 = nb[0];

    for (int i = wid; i < NN; i += nwv) {
        int vv = bc[i];
        int s = (i >> 7) * CAP + (vv >> 16);
        int n = vv & 0xFFFF;
        float a0 = 0.f, a1 = 0.f, a2 = 0.f, a3 = 0.f;
        if (q == 0) {
            uint2 u = mdq[i * 16 + f4];
            ACC4(u);
        }
        for (int e = 0; e < n; e += 16) {
            int e0 = e + q, e1 = e + 4 + q, e2 = e + 8 + q, e3 = e + 12 + q;
            int r0 = prow[s + (e0 < n ? e0 : 0)];
            int r1 = prow[s + (e1 < n ? e1 : 0)];
            int r2 = prow[s + (e2 < n ? e2 : 0)];
            int r3 = prow[s + (e3 < n ? e3 : 0)];
            uint2 u0 = mdq[r0 * 16 + f4];
            uint2 u1 = mdq[r1 * 16 + f4];
            uint2 u2 = mdq[r2 * 16 + f4];
            uint2 u3 = mdq[r3 * 16 + f4];
            if (e1 >= n) { u1.x = 0u; u1.y = 0u; }
            if (e2 >= n) { u2.x = 0u; u2.y = 0u; }
            if (e3 >= n) { u3.x = 0u; u3.y = 0u; }
            if (e0 >= n) { u0.x = 0u; u0.y = 0u; }
            ACC4(u0); ACC4(u1); ACC4(u2); ACC4(u3);
        }
        a0 += __shfl_xor(a0, 32, 64); a1 += __shfl_xor(a1, 32, 64);
        a2 += __shfl_xor(a2, 32, 64); a3 += __shfl_xor(a3, 32, 64);
        a0 += __shfl_xor(a0, 16, 64); a1 += __shfl_xor(a1, 16, 64);
        a2 += __shfl_xor(a2, 16, 64); a3 += __shfl_xor(a3, 16, 64);

        float di = dinv[i];
        float v0 = fmaxf(di * a0 + bj.x, 0.f);
        float v1 = fmaxf(di * a1 + bj.y, 0.f);
        float v2 = fmaxf(di * a2 + bj.z, 0.f);
        float v3 = fmaxf(di * a3 + bj.w, 0.f);

        float a  = v0 * wn.x  + v1 * wn.y  + v2 * wn.z  + v3 * wn.w;
        float s1 = v0 * we1.x + v1 * we1.y + v2 * we1.z + v3 * we1.w;
        float s2 = v0 * we2.x + v1 * we2.y + v2 * we2.z + v3 * we2.w;
        #pragma unroll
        for (int off = 8; off; off >>= 1) {
            a  += __shfl_xor(a,  off, 64);
            s1 += __shfl_xor(s1, off, 64);
            s2 += __shfl_xor(s2, off, 64);
        }
        if (lane == 0) {
            out_node[i] = 1.f / (1.f + expf(-(a + nb0)));
            ssrc[i] = s1;
            sdst[i] = s2;
        }
    }
}

// ---------------- edge scores (x4 vectorized) -------------------------------

__global__ __launch_bounds__(256) void k_edge(const int4* __restrict__ row4, const int4* __restrict__ col4,
                                              const float* __restrict__ ssrc, const float* __restrict__ sdst,
                                              const float* __restrict__ eb, float4* __restrict__ out4) {
    constexpr int NQ = EE / 4;
    int i = blockIdx.x * 256 + threadIdx.x;
    if (i >= NQ) return;
    float eb0 = eb[0];
    int4 r = row4[i], c = col4[i];
    float4 o;
    float z;
    z = ssrc[r.x] + sdst[c.x] + eb0; o.x = 1.f / (1.f + expf(-z));
    z = ssrc[r.y] + sdst[c.y] + eb0; o.y = 1.f / (1.f + expf(-z));
    z = ssrc[r.z] + sdst[c.z] + eb0; o.z = 1.f / (1.f + expf(-z));
    z = ssrc[r.w] + sdst[c.w] + eb0; o.w = 1.f / (1.f + expf(-z));
    out4[i] = o;
}

extern "C" void kernel_launch(void* const* d_in, const int* in_sizes, int n_in,
                              void* d_out, int out_size, void* d_ws, size_t ws_size,
                              hipStream_t stream) {
    const float* x    = (const float*)d_in[0];
    const int*   ei   = (const int*)d_in[1];
    const float* fc_w = (const float*)d_in[2];
    const float* fc_b = (const float*)d_in[3];
    const float* c1w  = (const float*)d_in[4];
    const float* c1b  = (const float*)d_in[5];
    const float* c2w  = (const float*)d_in[6];
    const float* c2b  = (const float*)d_in[7];
    const float* nw   = (const float*)d_in[8];
    const float* nb   = (const float*)d_in[9];
    const float* ew   = (const float*)d_in[10];
    const float* eb   = (const float*)d_in[11];
    const int* row = ei;        // edge_index[0]
    const int* col = ei + EE;   // edge_index[1]

    // workspace layout (4B units): ~47 MB total
    constexpr int NP = 100352;
    float* ws   = (float*)d_ws;
    float* dinv = ws;                               // NP
    int*   bc   = (int*)(ws + NP);                  // NP
    int*   gcur = (int*)(ws + 2 * NP);              // 1024
    float* wc   = ws + 2 * NP + 1024;               // 8192 (fc_w @ W1)
    float* bvec = wc + 8192;                        // 64 (+pad to 128)
    int*   ebuf = (int*)(bvec + 128);               // NBUCK*CAP
    float* A    = (float*)(ebuf + NBUCK * CAP);     // h1 [N*HID] f32
    unsigned short* Bbf = (unsigned short*)(A + (size_t)NN * HID);  // md bf16
    float* ssrc = A;                                // alias: A dead after k_mm(conv2)
    float* sdst = A + NP;

    float* out_edge = (float*)d_out;
    float* out_node = out_edge + EE;

    const int nbG = (NN + 63) / 64;             // 1563 GEMM tiles (64 rows each)
    const int nbC = (EE + CHUNK - 1) / CHUNK;   // 391 multisplit chunks
    const int nbQ = (EE / 4 + 255) / 256;       // 1563 edge-quad blocks

    // ---- bucketize + in-place node sort (builds CSR + dinv) ----
    k_zero    <<<(NBUCK + 255) / 256, 256, 0, stream>>>(gcur, NBUCK);
    k_bscatter<<<nbC, 256, 0, stream>>>(row, col, gcur, ebuf);
    k_bsortip <<<NBUCK, 256, 0, stream>>>(gcur, ebuf, bc, dinv);

    // ---- combined fc+conv1 weights, fused transform, conv1 gather ----
    k_wc    <<<33, 256, 0, stream>>>(fc_w, fc_b, c1w, wc, bvec);
    k_mmx   <<<nbG, 256, 0, stream>>>(x, wc, bvec, dinv, Bbf);
    k_gather<<<2048, 256, 0, stream>>>(Bbf, ebuf, bc, dinv, c1b, A);

    // ---- conv2 transform + gather fused with scores ----
    k_mm      <<<nbG, 256, 0, stream>>>(A, c2w, dinv, Bbf);
    k_gather2s<<<2048, 256, 0, stream>>>(Bbf, ebuf, bc, dinv, c2b,
                                         nw, nb, ew, out_node, ssrc, sdst);

    // ---- edge scores ----
    k_edge<<<nbQ, 256, 0, stream>>>((const int4*)row, (const int4*)col,
                                    ssrc, sdst, eb, (float4*)out_edge);
}

// Round 14
// 195.877 us; speedup vs baseline: 1.4544x; 1.0933x over previous
//
#include <hip/hip_runtime.h>
#include <math.h>

// Problem constants (from reference)
constexpr int NN  = 100000;   // nodes (= 6250 * 16, no row tail)
constexpr int EE  = 1600000;  // edges
constexpr int IND = 128;      // input dim
constexpr int HID = 64;       // hidden dim

constexpr int NBUCK = (NN + 127) / 128;   // 782 buckets of 128 nodes
constexpr int CAP   = 2432;               // bucket capacity (validated rounds 6-13)
constexpr int CHUNK = 4096;               // edges per multisplit block
constexpr int NTILE = NN / 16;            // 6250 MFMA row-tiles

using bf16x8 = __attribute__((ext_vector_type(8))) short;
using f32x4v = __attribute__((ext_vector_type(4))) float;

// bf16 helpers (round-to-nearest-even)
__device__ __forceinline__ unsigned short f2bf(float f) {
    union { float f; unsigned int u; } v; v.f = f;
    unsigned int r = (v.u + 0x7FFFu + ((v.u >> 16) & 1u)) >> 16;
    return (unsigned short)r;
}
// unpack a uint holding two bf16 (lo = bits 0..15, hi = bits 16..31)
__device__ __forceinline__ void unp(unsigned int u, float& lo, float& hi) {
    union { unsigned int x; float f; } a, c;
    a.x = u << 16; c.x = u & 0xFFFF0000u;
    lo = a.f; hi = c.f;
}

// accumulate one uint2 (4 bf16) into a0..a3
#define ACC4(u) do { float l_, h_; \
    unp((u).x, l_, h_); a0 += l_; a1 += h_; \
    unp((u).y, l_, h_); a2 += l_; a3 += h_; } while (0)

// ---------------- small zero ----------------

__global__ __launch_bounds__(256) void k_zero(int* __restrict__ p, int n) {
    int i = blockIdx.x * 256 + threadIdx.x;
    if (i < n) p[i] = 0;
}

// ---------------- bucketized multisplit -------------------------------------

__global__ __launch_bounds__(256) void k_bscatter(const int* __restrict__ row, const int* __restrict__ col,
                                                  int* __restrict__ gcur, int* __restrict__ ebuf) {
    __shared__ int lhist[NBUCK];
    __shared__ int lbase[NBUCK];
    __shared__ int lcur[NBUCK];
    const int tx = threadIdx.x;
    const int cbase = blockIdx.x * CHUNK;

    for (int b = tx; b < NBUCK; b += 256) lhist[b] = 0;
    __syncthreads();

    #pragma unroll
    for (int i = 0; i < CHUNK / 256; ++i) {
        int e = cbase + tx + i * 256;
        if (e < EE) atomicAdd(&lhist[col[e] >> 7], 1);
    }
    __syncthreads();

    for (int b = tx; b < NBUCK; b += 256) {
        int c = lhist[b];
        if (c) lbase[b] = atomicAdd(&gcur[b], c);
        lcur[b] = 0;
    }
    __syncthreads();

    #pragma unroll
    for (int i = 0; i < CHUNK / 256; ++i) {
        int e = cbase + tx + i * 256;
        if (e < EE) {
            int c = col[e];
            int b = c >> 7;
            int rank = atomicAdd(&lcur[b], 1);
            ebuf[b * CAP + lbase[b] + rank] = (row[e] << 7) | (c & 127);
        }
    }
}

// ---------------- in-place per-bucket node sort -----------------------------

__global__ __launch_bounds__(256) void k_bsortip(const int* __restrict__ gcur, int* __restrict__ ebuf,
                                                 int* __restrict__ bc, float* __restrict__ dinv) {
    __shared__ int ebl[CAP];
    __shared__ int h[128];
    __shared__ int sc[128];
    __shared__ int cur[128];
    const int tx = threadIdx.x;
    const int b = blockIdx.x;
    const int cnt = gcur[b];
    int* eb = ebuf + b * CAP;

    if (tx < 128) h[tx] = 0;
    for (int e = tx; e < cnt; e += 256) ebl[e] = eb[e];
    __syncthreads();
    for (int e = tx; e < cnt; e += 256) atomicAdd(&h[ebl[e] & 127], 1);
    __syncthreads();

    if (tx < 128) sc[tx] = h[tx];
    __syncthreads();
    #pragma unroll
    for (int o = 1; o < 128; o <<= 1) {
        int add = (tx < 128 && tx >= o) ? sc[tx - o] : 0;
        __syncthreads();
        if (tx < 128) sc[tx] += add;
        __syncthreads();
    }
    if (tx < 128) {
        int ex = sc[tx] - h[tx];
        cur[tx] = ex;
        int g = b * 128 + tx;
        if (g < NN) {
            bc[g]   = (ex << 16) | h[tx];
            dinv[g] = rsqrtf((float)(h[tx] + 1));   // +1 = self-loop
        }
    }
    __syncthreads();

    for (int e = tx; e < cnt; e += 256) {
        int v = ebl[e];
        int r = atomicAdd(&cur[v & 127], 1);
        eb[r] = v >> 7;
    }
}

// ---------------- combined weight: Wc^T (bf16) and bvec ---------------------
// Wc = fc_w @ W1 (exact algebraic fusion); stored TRANSPOSED in bf16 so the
// MFMA B-fragment is one contiguous uint4 load per (ntile, kchunk).

__global__ __launch_bounds__(256) void k_wc(const float* __restrict__ wfc, const float* __restrict__ bfc,
                                            const float* __restrict__ w1,
                                            unsigned short* __restrict__ wct, float* __restrict__ bvec) {
    int b = blockIdx.x, tx = threadIdx.x;
    if (b < 32) {
        int idx = b * 256 + tx;          // 0..8191
        int k = idx >> 6, c = idx & 63;
        float acc = 0.f;
        #pragma unroll 8
        for (int j = 0; j < 64; ++j) acc += wfc[k * HID + j] * w1[j * HID + c];
        wct[c * IND + k] = f2bf(acc);    // transposed: [c][k]
    } else if (tx < 64) {
        float acc = 0.f;
        #pragma unroll 8
        for (int j = 0; j < 64; ++j) acc += bfc[j] * w1[j * HID + tx];
        bvec[tx] = acc;
    }
}

// ---------------- fused fc+conv1 transform via MFMA -------------------------
// mdb = bf16((x @ Wc + bvec) * dinv). One wave per 16-row tile:
// A-frag: lane holds x_bf16[row0 + (l&15)][kc*32 + (l>>4)*8 + i] (cvt in-reg).
// B-frag: lane holds Wc[kc*32 + (l>>4)*8 + i][t*16 + (l&15)] = wct row read.
// Shared-k-permutation argument makes the fragment k-order assumption safe.
// D: md[row0 + (l>>4)*4 + r][t*16 + (l&15)]  (HW-verified C/D mapping).

__global__ __launch_bounds__(256) void k_mmx(const float* __restrict__ x,
        const unsigned short* __restrict__ wct, const float* __restrict__ bvec,
        const float* __restrict__ dinv, unsigned short* __restrict__ mdb) {
    const int tx = threadIdx.x;
    const int lane = tx & 63;
    const int wv = tx >> 6;
    const int l15 = lane & 15, g = lane >> 4;
    const int tile = blockIdx.x * 4 + wv;
    if (tile >= NTILE) return;           // no barriers in this kernel
    const int row0 = tile * 16;

    // B fragments: 4 n-tiles x 4 k-chunks (16 KB table, L1/L2-hot)
    bf16x8 bf[4][4];
    #pragma unroll
    for (int t = 0; t < 4; ++t) {
        const unsigned short* bp = wct + (t * 16 + l15) * IND + g * 8;
        #pragma unroll
        for (int kc = 0; kc < 4; ++kc)
            bf[t][kc] = *(const bf16x8*)(bp + kc * 32);
    }

    // A fragments: 8 consecutive f32 of x, converted to bf16 in-register
    const float* ap = x + (row0 + l15) * IND + g * 8;
    bf16x8 af[4];
    #pragma unroll
    for (int kc = 0; kc < 4; ++kc) {
        float4 lo = *(const float4*)(ap + kc * 32);
        float4 hi = *(const float4*)(ap + kc * 32 + 4);
        bf16x8 f;
        f[0] = (short)f2bf(lo.x); f[1] = (short)f2bf(lo.y);
        f[2] = (short)f2bf(lo.z); f[3] = (short)f2bf(lo.w);
        f[4] = (short)f2bf(hi.x); f[5] = (short)f2bf(hi.y);
        f[6] = (short)f2bf(hi.z); f[7] = (short)f2bf(hi.w);
        af[kc] = f;
    }

    // accumulate (bias init: depends only on output col = t*16 + l15)
    f32x4v acc[4];
    #pragma unroll
    for (int t = 0; t < 4; ++t) {
        float bv = bvec[t * 16 + l15];
        acc[t][0] = bv; acc[t][1] = bv; acc[t][2] = bv; acc[t][3] = bv;
    }
    #pragma unroll
    for (int kc = 0; kc < 4; ++kc) {
        #pragma unroll
        for (int t = 0; t < 4; ++t)
            acc[t] = __builtin_amdgcn_mfma_f32_16x16x32_bf16(af[kc], bf[t][kc], acc[t], 0, 0, 0);
    }

    // epilogue: row = row0 + g*4 + r, col = t*16 + l15
    #pragma unroll
    for (int r = 0; r < 4; ++r) {
        int rowg = row0 + g * 4 + r;
        float di = dinv[rowg];
        #pragma unroll
        for (int t = 0; t < 4; ++t)
            mdb[rowg * HID + t * 16 + l15] = f2bf(acc[t][r] * di);
    }
}

// ---------------- conv2 transform: mdb = bf16((h1 @ W2) * dinv) -------------
// (unchanged round-13 VALU version; MFMA port held back pending absmax check)

__global__ __launch_bounds__(256) void k_mm(const float* __restrict__ hin, const float* __restrict__ w,
                                            const float* __restrict__ dinv,
                                            unsigned short* __restrict__ mdb) {
    __shared__ float sw[HID * HID];     // 16 KB
    const int tx = threadIdx.x;
    for (int i = tx; i < HID * HID; i += 256) sw[i] = w[i];

    const int tc = tx & 15;
    const int gr = tx >> 4;
    const int c0 = tc * 4;
    const int rbase = blockIdx.x * 64 + gr * 4;

    int o[4];
    #pragma unroll
    for (int i = 0; i < 4; ++i) {
        int rg = rbase + i;
        o[i] = (rg < NN ? rg : 0) * HID;
    }
    __syncthreads();

    float acc[4][4] = {};

    #pragma unroll 2
    for (int kk = 0; kk < HID; kk += 4) {
        float4 a[4];
        #pragma unroll
        for (int i = 0; i < 4; ++i) a[i] = *(const float4*)(hin + o[i] + kk);
        float4 b0 = *(const float4*)&sw[(kk + 0) * HID + c0];
        float4 b1 = *(const float4*)&sw[(kk + 1) * HID + c0];
        float4 b2 = *(const float4*)&sw[(kk + 2) * HID + c0];
        float4 b3 = *(const float4*)&sw[(kk + 3) * HID + c0];
        #pragma unroll
        for (int i = 0; i < 4; ++i) {
            acc[i][0] += a[i].x * b0.x + a[i].y * b1.x + a[i].z * b2.x + a[i].w * b3.x;
            acc[i][1] += a[i].x * b0.y + a[i].y * b1.y + a[i].z * b2.y + a[i].w * b3.y;
            acc[i][2] += a[i].x * b0.z + a[i].y * b1.z + a[i].z * b2.z + a[i].w * b3.z;
            acc[i][3] += a[i].x * b0.w + a[i].y * b1.w + a[i].z * b2.w + a[i].w * b3.w;
        }
    }

    #pragma unroll
    for (int i = 0; i < 4; ++i) {
        int rg = rbase + i;
        if (rg < NN) {
            float di = dinv[rg];
            ushort4 o4;
            o4.x = f2bf(acc[i][0] * di); o4.y = f2bf(acc[i][1] * di);
            o4.z = f2bf(acc[i][2] * di); o4.w = f2bf(acc[i][3] * di);
            *(ushort4*)&mdb[rg * HID + c0] = o4;
        }
    }
}

// ---------------- gather conv1: 16-edge masked passes (round-13) ------------

__global__ __launch_bounds__(256) void k_gather(const unsigned short* __restrict__ mdb,
                                                const int* __restrict__ prow, const int* __restrict__ bc,
                                                const float* __restrict__ dinv, const float* __restrict__ b,
                                                float* __restrict__ hout) {
    const uint2* mdq = (const uint2*)mdb;      // 4 bf16 per element
    int lane = threadIdx.x & 63;
    int q    = lane >> 4;
    int f4   = lane & 15;
    int wid  = (blockIdx.x * blockDim.x + threadIdx.x) >> 6;
    int nwv  = (gridDim.x * blockDim.x) >> 6;
    float4 bj = *(const float4*)&b[f4 * 4];

    for (int i = wid; i < NN; i += nwv) {
        int vv = bc[i];
        int s = (i >> 7) * CAP + (vv >> 16);
        int n = vv & 0xFFFF;
        float a0 = 0.f, a1 = 0.f, a2 = 0.f, a3 = 0.f;
        if (q == 0) {                      // self-loop term, counted once
            uint2 u = mdq[i * 16 + f4];
            ACC4(u);
        }
        for (int e = 0; e < n; e += 16) {
            int e0 = e + q, e1 = e + 4 + q, e2 = e + 8 + q, e3 = e + 12 + q;
            int r0 = prow[s + (e0 < n ? e0 : 0)];
            int r1 = prow[s + (e1 < n ? e1 : 0)];
            int r2 = prow[s + (e2 < n ? e2 : 0)];
            int r3 = prow[s + (e3 < n ? e3 : 0)];
            uint2 u0 = mdq[r0 * 16 + f4];
            uint2 u1 = mdq[r1 * 16 + f4];
            uint2 u2 = mdq[r2 * 16 + f4];
            uint2 u3 = mdq[r3 * 16 + f4];
            if (e1 >= n) { u1.x = 0u; u1.y = 0u; }
            if (e2 >= n) { u2.x = 0u; u2.y = 0u; }
            if (e3 >= n) { u3.x = 0u; u3.y = 0u; }
            if (e0 >= n) { u0.x = 0u; u0.y = 0u; }
            ACC4(u0); ACC4(u1); ACC4(u2); ACC4(u3);
        }
        // merge quarters
        a0 += __shfl_xor(a0, 32, 64); a1 += __shfl_xor(a1, 32, 64);
        a2 += __shfl_xor(a2, 32, 64); a3 += __shfl_xor(a3, 32, 64);
        a0 += __shfl_xor(a0, 16, 64); a1 += __shfl_xor(a1, 16, 64);
        a2 += __shfl_xor(a2, 16, 64); a3 += __shfl_xor(a3, 16, 64);

        float di = dinv[i];
        float4 o;
        o.x = fmaxf(di * a0 + bj.x, 0.f);
        o.y = fmaxf(di * a1 + bj.y, 0.f);
        o.z = fmaxf(di * a2 + bj.z, 0.f);
        o.w = fmaxf(di * a3 + bj.w, 0.f);
        if (q == 0) *(float4*)&hout[i * HID + f4 * 4] = o;
    }
}

// ---------------- gather conv2 fused with scores (round-13) -----------------

__global__ __launch_bounds__(256) void k_gather2s(const unsigned short* __restrict__ mdb,
        const int* __restrict__ prow, const int* __restrict__ bc, const float* __restrict__ dinv,
        const float* __restrict__ b, const float* __restrict__ nw, const float* __restrict__ nb,
        const float* __restrict__ ew, float* __restrict__ out_node,
        float* __restrict__ ssrc, float* __restrict__ sdst) {
    const uint2* mdq = (const uint2*)mdb;
    int lane = threadIdx.x & 63;
    int q    = lane >> 4;
    int f4   = lane & 15;
    int wid  = (blockIdx.x * blockDim.x + threadIdx.x) >> 6;
    int nwv  = (gridDim.x * blockDim.x) >> 6;
    float4 bj  = *(const float4*)&b[f4 * 4];
    float4 wn  = *(const float4*)&nw[f4 * 4];
    float4 we1 = *(const float4*)&ew[f4 * 4];
    float4 we2 = *(const float4*)&ew[64 + f4 * 4];
    float nb0 = nb[0];

    for (int i = wid; i < NN; i += nwv) {
        int vv = bc[i];
        int s = (i >> 7) * CAP + (vv >> 16);
        int n = vv & 0xFFFF;
        float a0 = 0.f, a1 = 0.f, a2 = 0.f, a3 = 0.f;
        if (q == 0) {
            uint2 u = mdq[i * 16 + f4];
            ACC4(u);
        }
        for (int e = 0; e < n; e += 16) {
            int e0 = e + q, e1 = e + 4 + q, e2 = e + 8 + q, e3 = e + 12 + q;
            int r0 = prow[s + (e0 < n ? e0 : 0)];
            int r1 = prow[s + (e1 < n ? e1 : 0)];
            int r2 = prow[s + (e2 < n ? e2 : 0)];
            int r3 = prow[s + (e3 < n ? e3 : 0)];
            uint2 u0 = mdq[r0 * 16 + f4];
            uint2 u1 = mdq[r1 * 16 + f4];
            uint2 u2 = mdq[r2 * 16 + f4];
            uint2 u3 = mdq[r3 * 16 + f4];
            if (e1 >= n) { u1.x = 0u; u1.y = 0u; }
            if (e2 >= n) { u2.x = 0u; u2.y = 0u; }
            if (e3 >= n) { u3.x = 0u; u3.y = 0u; }
            if (e0 >= n) { u0.x = 0u; u0.y = 0u; }
            ACC4(u0); ACC4(u1); ACC4(u2); ACC4(u3);
        }
        a0 += __shfl_xor(a0, 32, 64); a1 += __shfl_xor(a1, 32, 64);
        a2 += __shfl_xor(a2, 32, 64); a3 += __shfl_xor(a3, 32, 64);
        a0 += __shfl_xor(a0, 16, 64); a1 += __shfl_xor(a1, 16, 64);
        a2 += __shfl_xor(a2, 16, 64); a3 += __shfl_xor(a3, 16, 64);

        float di = dinv[i];
        float v0 = fmaxf(di * a0 + bj.x, 0.f);
        float v1 = fmaxf(di * a1 + bj.y, 0.f);
        float v2 = fmaxf(di * a2 + bj.z, 0.f);
        float v3 = fmaxf(di * a3 + bj.w, 0.f);

        float a  = v0 * wn.x  + v1 * wn.y  + v2 * wn.z  + v3 * wn.w;
        float s1 = v0 * we1.x + v1 * we1.y + v2 * we1.z + v3 * we1.w;
        float s2 = v0 * we2.x + v1 * we2.y + v2 * we2.z + v3 * we2.w;
        #pragma unroll
        for (int off = 8; off; off >>= 1) {
            a  += __shfl_xor(a,  off, 64);
            s1 += __shfl_xor(s1, off, 64);
            s2 += __shfl_xor(s2, off, 64);
        }
        if (lane == 0) {
            out_node[i] = 1.f / (1.f + expf(-(a + nb0)));
            ssrc[i] = s1;
            sdst[i] = s2;
        }
    }
}

// ---------------- edge scores (x4 vectorized) -------------------------------

__global__ __launch_bounds__(256) void k_edge(const int4* __restrict__ row4, const int4* __restrict__ col4,
                                              const float* __restrict__ ssrc, const float* __restrict__ sdst,
                                              const float* __restrict__ eb, float4* __restrict__ out4) {
    constexpr int NQ = EE / 4;
    int i = blockIdx.x * 256 + threadIdx.x;
    if (i >= NQ) return;
    float eb0 = eb[0];
    int4 r = row4[i], c = col4[i];
    float4 o;
    float z;
    z = ssrc[r.x] + sdst[c.x] + eb0; o.x = 1.f / (1.f + expf(-z));
    z = ssrc[r.y] + sdst[c.y] + eb0; o.y = 1.f / (1.f + expf(-z));
    z = ssrc[r.z] + sdst[c.z] + eb0; o.z = 1.f / (1.f + expf(-z));
    z = ssrc[r.w] + sdst[c.w] + eb0; o.w = 1.f / (1.f + expf(-z));
    out4[i] = o;
}

extern "C" void kernel_launch(void* const* d_in, const int* in_sizes, int n_in,
                              void* d_out, int out_size, void* d_ws, size_t ws_size,
                              hipStream_t stream) {
    const float* x    = (const float*)d_in[0];
    const int*   ei   = (const int*)d_in[1];
    const float* fc_w = (const float*)d_in[2];
    const float* fc_b = (const float*)d_in[3];
    const float* c1w  = (const float*)d_in[4];
    const float* c1b  = (const float*)d_in[5];
    const float* c2w  = (const float*)d_in[6];
    const float* c2b  = (const float*)d_in[7];
    const float* nw   = (const float*)d_in[8];
    const float* nb   = (const float*)d_in[9];
    const float* ew   = (const float*)d_in[10];
    const float* eb   = (const float*)d_in[11];
    const int* row = ei;        // edge_index[0]
    const int* col = ei + EE;   // edge_index[1]

    // workspace layout (4B units): ~47 MB total
    constexpr int NP = 100352;
    float* ws   = (float*)d_ws;
    float* dinv = ws;                               // NP
    int*   bc   = (int*)(ws + NP);                  // NP
    int*   gcur = (int*)(ws + 2 * NP);              // 1024
    unsigned short* wct = (unsigned short*)(ws + 2 * NP + 1024);  // 8192 bf16 (Wc^T) = 4096 floats
    float* bvec = ws + 2 * NP + 1024 + 4096;        // 64 (+pad to 128)
    int*   ebuf = (int*)(bvec + 128);               // NBUCK*CAP
    float* A    = (float*)(ebuf + NBUCK * CAP);     // h1 [N*HID] f32
    unsigned short* Bbf = (unsigned short*)(A + (size_t)NN * HID);  // md bf16
    float* ssrc = A;                                // alias: A dead after k_mm(conv2)
    float* sdst = A + NP;

    float* out_edge = (float*)d_out;
    float* out_node = out_edge + EE;

    const int nbG = (NN + 63) / 64;             // 1563 GEMM tiles (64 rows each)
    const int nbC = (EE + CHUNK - 1) / CHUNK;   // 391 multisplit chunks
    const int nbQ = (EE / 4 + 255) / 256;       // 1563 edge-quad blocks
    const int nbM = (NTILE + 3) / 4;            // 1563 MFMA blocks (4 waves = 4 tiles)

    // ---- bucketize + in-place node sort (builds CSR + dinv) ----
    k_zero    <<<(NBUCK + 255) / 256, 256, 0, stream>>>(gcur, NBUCK);
    k_bscatter<<<nbC, 256, 0, stream>>>(row, col, gcur, ebuf);
    k_bsortip <<<NBUCK, 256, 0, stream>>>(gcur, ebuf, bc, dinv);

    // ---- combined fc+conv1 weights (bf16 Wc^T), MFMA transform, gather ----
    k_wc    <<<33, 256, 0, stream>>>(fc_w, fc_b, c1w, wct, bvec);
    k_mmx   <<<nbM, 256, 0, stream>>>(x, wct, bvec, dinv, Bbf);
    k_gather<<<2048, 256, 0, stream>>>(Bbf, ebuf, bc, dinv, c1b, A);

    // ---- conv2 transform + gather fused with scores ----
    k_mm      <<<nbG, 256, 0, stream>>>(A, c2w, dinv, Bbf);
    k_gather2s<<<2048, 256, 0, stream>>>(Bbf, ebuf, bc, dinv, c2b,
                                         nw, nb, ew, out_node, ssrc, sdst);

    // ---- edge scores ----
    k_edge<<<nbQ, 256, 0, stream>>>((const int4*)row, (const int4*)col,
                                    ssrc, sdst, eb, (float4*)out_edge);
}

// Round 15
// 187.242 us; speedup vs baseline: 1.5214x; 1.0461x over previous
//
#include <hip/hip_runtime.h>
#include <math.h>

// Problem constants (from reference)
constexpr int NN  = 100000;   // nodes (= 6250 * 16, no row tail)
constexpr int EE  = 1600000;  // edges
constexpr int IND = 128;      // input dim
constexpr int HID = 64;       // hidden dim

constexpr int NBUCK = (NN + 127) / 128;   // 782 buckets of 128 nodes
constexpr int CAP   = 2432;               // bucket capacity (validated rounds 6-14)
constexpr int CHUNK = 4096;               // edges per multisplit block
constexpr int NTILE = NN / 16;            // 6250 MFMA row-tiles

using bf16x8 = __attribute__((ext_vector_type(8))) short;
using f32x4v = __attribute__((ext_vector_type(4))) float;

// bf16 helpers (round-to-nearest-even)
__device__ __forceinline__ unsigned short f2bf(float f) {
    union { float f; unsigned int u; } v; v.f = f;
    unsigned int r = (v.u + 0x7FFFu + ((v.u >> 16) & 1u)) >> 16;
    return (unsigned short)r;
}
// unpack a uint holding two bf16 (lo = bits 0..15, hi = bits 16..31)
__device__ __forceinline__ void unp(unsigned int u, float& lo, float& hi) {
    union { unsigned int x; float f; } a, c;
    a.x = u << 16; c.x = u & 0xFFFF0000u;
    lo = a.f; hi = c.f;
}

// accumulate one uint2 (4 bf16) into a0..a3
#define ACC4(u) do { float l_, h_; \
    unp((u).x, l_, h_); a0 += l_; a1 += h_; \
    unp((u).y, l_, h_); a2 += l_; a3 += h_; } while (0)

// ---------------- small zero ----------------

__global__ __launch_bounds__(256) void k_zero(int* __restrict__ p, int n) {
    int i = blockIdx.x * 256 + threadIdx.x;
    if (i < n) p[i] = 0;
}

// ---------------- bucketized multisplit -------------------------------------

__global__ __launch_bounds__(256) void k_bscatter(const int* __restrict__ row, const int* __restrict__ col,
                                                  int* __restrict__ gcur, int* __restrict__ ebuf) {
    __shared__ int lhist[NBUCK];
    __shared__ int lbase[NBUCK];
    __shared__ int lcur[NBUCK];
    const int tx = threadIdx.x;
    const int cbase = blockIdx.x * CHUNK;

    for (int b = tx; b < NBUCK; b += 256) lhist[b] = 0;
    __syncthreads();

    #pragma unroll
    for (int i = 0; i < CHUNK / 256; ++i) {
        int e = cbase + tx + i * 256;
        if (e < EE) atomicAdd(&lhist[col[e] >> 7], 1);
    }
    __syncthreads();

    for (int b = tx; b < NBUCK; b += 256) {
        int c = lhist[b];
        if (c) lbase[b] = atomicAdd(&gcur[b], c);
        lcur[b] = 0;
    }
    __syncthreads();

    #pragma unroll
    for (int i = 0; i < CHUNK / 256; ++i) {
        int e = cbase + tx + i * 256;
        if (e < EE) {
            int c = col[e];
            int b = c >> 7;
            int rank = atomicAdd(&lcur[b], 1);
            ebuf[b * CAP + lbase[b] + rank] = (row[e] << 7) | (c & 127);
        }
    }
}

// ---------------- in-place per-bucket node sort -----------------------------

__global__ __launch_bounds__(256) void k_bsortip(const int* __restrict__ gcur, int* __restrict__ ebuf,
                                                 int* __restrict__ bc, float* __restrict__ dinv) {
    __shared__ int ebl[CAP];
    __shared__ int h[128];
    __shared__ int sc[128];
    __shared__ int cur[128];
    const int tx = threadIdx.x;
    const int b = blockIdx.x;
    const int cnt = gcur[b];
    int* eb = ebuf + b * CAP;

    if (tx < 128) h[tx] = 0;
    for (int e = tx; e < cnt; e += 256) ebl[e] = eb[e];
    __syncthreads();
    for (int e = tx; e < cnt; e += 256) atomicAdd(&h[ebl[e] & 127], 1);
    __syncthreads();

    if (tx < 128) sc[tx] = h[tx];
    __syncthreads();
    #pragma unroll
    for (int o = 1; o < 128; o <<= 1) {
        int add = (tx < 128 && tx >= o) ? sc[tx - o] : 0;
        __syncthreads();
        if (tx < 128) sc[tx] += add;
        __syncthreads();
    }
    if (tx < 128) {
        int ex = sc[tx] - h[tx];
        cur[tx] = ex;
        int g = b * 128 + tx;
        if (g < NN) {
            bc[g]   = (ex << 16) | h[tx];
            dinv[g] = rsqrtf((float)(h[tx] + 1));   // +1 = self-loop
        }
    }
    __syncthreads();

    for (int e = tx; e < cnt; e += 256) {
        int v = ebl[e];
        int r = atomicAdd(&cur[v & 127], 1);
        eb[r] = v >> 7;
    }
}

// ---------------- weight prep: Wc^T bf16, bvec, W2^T bf16 -------------------
// Wc = fc_w @ W1 (exact algebraic fusion). Both transposed weights stored
// [col][k] so MFMA B-fragments are contiguous bf16x8 loads.

__global__ __launch_bounds__(256) void k_wc(const float* __restrict__ wfc, const float* __restrict__ bfc,
                                            const float* __restrict__ w1, const float* __restrict__ w2,
                                            unsigned short* __restrict__ wct, float* __restrict__ bvec,
                                            unsigned short* __restrict__ w2t) {
    int b = blockIdx.x, tx = threadIdx.x;
    if (b < 32) {
        int idx = b * 256 + tx;          // 0..8191
        int k = idx >> 6, c = idx & 63;
        float acc = 0.f;
        #pragma unroll 8
        for (int j = 0; j < 64; ++j) acc += wfc[k * HID + j] * w1[j * HID + c];
        wct[c * IND + k] = f2bf(acc);    // transposed: [c][k]
    } else if (b < 48) {
        int idx = (b - 32) * 256 + tx;   // 0..4095
        int k = idx >> 6, c = idx & 63;
        w2t[c * HID + k] = f2bf(w2[k * HID + c]);
    } else if (tx < 64) {
        float acc = 0.f;
        #pragma unroll 8
        for (int j = 0; j < 64; ++j) acc += bfc[j] * w1[j * HID + tx];
        bvec[tx] = acc;
    }
}

// ---------------- fused fc+conv1 transform via MFMA (round-14 proven) -------

__global__ __launch_bounds__(256) void k_mmx(const float* __restrict__ x,
        const unsigned short* __restrict__ wct, const float* __restrict__ bvec,
        const float* __restrict__ dinv, unsigned short* __restrict__ mdb) {
    const int tx = threadIdx.x;
    const int lane = tx & 63;
    const int wv = tx >> 6;
    const int l15 = lane & 15, g = lane >> 4;
    const int tile = blockIdx.x * 4 + wv;
    if (tile >= NTILE) return;           // no barriers in this kernel
    const int row0 = tile * 16;

    // B fragments: 4 n-tiles x 4 k-chunks (16 KB table, L1/L2-hot)
    bf16x8 bf[4][4];
    #pragma unroll
    for (int t = 0; t < 4; ++t) {
        const unsigned short* bp = wct + (t * 16 + l15) * IND + g * 8;
        #pragma unroll
        for (int kc = 0; kc < 4; ++kc)
            bf[t][kc] = *(const bf16x8*)(bp + kc * 32);
    }

    // A fragments: 8 consecutive f32 of x, converted to bf16 in-register
    const float* ap = x + (row0 + l15) * IND + g * 8;
    bf16x8 af[4];
    #pragma unroll
    for (int kc = 0; kc < 4; ++kc) {
        float4 lo = *(const float4*)(ap + kc * 32);
        float4 hi = *(const float4*)(ap + kc * 32 + 4);
        bf16x8 f;
        f[0] = (short)f2bf(lo.x); f[1] = (short)f2bf(lo.y);
        f[2] = (short)f2bf(lo.z); f[3] = (short)f2bf(lo.w);
        f[4] = (short)f2bf(hi.x); f[5] = (short)f2bf(hi.y);
        f[6] = (short)f2bf(hi.z); f[7] = (short)f2bf(hi.w);
        af[kc] = f;
    }

    // accumulate (bias init: depends only on output col = t*16 + l15)
    f32x4v acc[4];
    #pragma unroll
    for (int t = 0; t < 4; ++t) {
        float bv = bvec[t * 16 + l15];
        acc[t][0] = bv; acc[t][1] = bv; acc[t][2] = bv; acc[t][3] = bv;
    }
    #pragma unroll
    for (int kc = 0; kc < 4; ++kc) {
        #pragma unroll
        for (int t = 0; t < 4; ++t)
            acc[t] = __builtin_amdgcn_mfma_f32_16x16x32_bf16(af[kc], bf[t][kc], acc[t], 0, 0, 0);
    }

    // epilogue: row = row0 + g*4 + r, col = t*16 + l15
    #pragma unroll
    for (int r = 0; r < 4; ++r) {
        int rowg = row0 + g * 4 + r;
        float di = dinv[rowg];
        #pragma unroll
        for (int t = 0; t < 4; ++t)
            mdb[rowg * HID + t * 16 + l15] = f2bf(acc[t][r] * di);
    }
}

// ---------------- conv2 transform via MFMA: mdb = bf16((h1b @ W2) * dinv) ---
// Same structure as k_mmx; A (h1) is already bf16 -> direct bf16x8 loads.

__global__ __launch_bounds__(256) void k_mm2x(const unsigned short* __restrict__ h1b,
        const unsigned short* __restrict__ w2t, const float* __restrict__ dinv,
        unsigned short* __restrict__ mdb) {
    const int tx = threadIdx.x;
    const int lane = tx & 63;
    const int wv = tx >> 6;
    const int l15 = lane & 15, g = lane >> 4;
    const int tile = blockIdx.x * 4 + wv;
    if (tile >= NTILE) return;
    const int row0 = tile * 16;

    // B fragments: 4 n-tiles x 2 k-chunks (8 KB table, L1-hot)
    bf16x8 bf[4][2];
    #pragma unroll
    for (int t = 0; t < 4; ++t) {
        const unsigned short* bp = w2t + (t * 16 + l15) * HID + g * 8;
        #pragma unroll
        for (int kc = 0; kc < 2; ++kc)
            bf[t][kc] = *(const bf16x8*)(bp + kc * 32);
    }

    // A fragments: direct bf16 loads of h1 rows
    const unsigned short* ap = h1b + (row0 + l15) * HID + g * 8;
    bf16x8 af[2];
    af[0] = *(const bf16x8*)(ap);
    af[1] = *(const bf16x8*)(ap + 32);

    f32x4v acc[4] = {};
    #pragma unroll
    for (int kc = 0; kc < 2; ++kc) {
        #pragma unroll
        for (int t = 0; t < 4; ++t)
            acc[t] = __builtin_amdgcn_mfma_f32_16x16x32_bf16(af[kc], bf[t][kc], acc[t], 0, 0, 0);
    }

    #pragma unroll
    for (int r = 0; r < 4; ++r) {
        int rowg = row0 + g * 4 + r;
        float di = dinv[rowg];
        #pragma unroll
        for (int t = 0; t < 4; ++t)
            mdb[rowg * HID + t * 16 + l15] = f2bf(acc[t][r] * di);
    }
}

// ---------------- gather conv1: h1 (bf16 out) = relu(...) -------------------
// 16-edge masked passes (round-13 structure); output now bf16 (ushort4),
// halving WRITE traffic and feeding k_mm2x's A-operand directly.

__global__ __launch_bounds__(256) void k_gather(const unsigned short* __restrict__ mdb,
                                                const int* __restrict__ prow, const int* __restrict__ bc,
                                                const float* __restrict__ dinv, const float* __restrict__ b,
                                                unsigned short* __restrict__ hout) {
    const uint2* mdq = (const uint2*)mdb;      // 4 bf16 per element
    int lane = threadIdx.x & 63;
    int q    = lane >> 4;
    int f4   = lane & 15;
    int wid  = (blockIdx.x * blockDim.x + threadIdx.x) >> 6;
    int nwv  = (gridDim.x * blockDim.x) >> 6;
    float4 bj = *(const float4*)&b[f4 * 4];

    for (int i = wid; i < NN; i += nwv) {
        int vv = bc[i];
        int s = (i >> 7) * CAP + (vv >> 16);
        int n = vv & 0xFFFF;
        float a0 = 0.f, a1 = 0.f, a2 = 0.f, a3 = 0.f;
        if (q == 0) {                      // self-loop term, counted once
            uint2 u = mdq[i * 16 + f4];
            ACC4(u);
        }
        for (int e = 0; e < n; e += 16) {
            int e0 = e + q, e1 = e + 4 + q, e2 = e + 8 + q, e3 = e + 12 + q;
            int r0 = prow[s + (e0 < n ? e0 : 0)];
            int r1 = prow[s + (e1 < n ? e1 : 0)];
            int r2 = prow[s + (e2 < n ? e2 : 0)];
            int r3 = prow[s + (e3 < n ? e3 : 0)];
            uint2 u0 = mdq[r0 * 16 + f4];
            uint2 u1 = mdq[r1 * 16 + f4];
            uint2 u2 = mdq[r2 * 16 + f4];
            uint2 u3 = mdq[r3 * 16 + f4];
            if (e1 >= n) { u1.x = 0u; u1.y = 0u; }
            if (e2 >= n) { u2.x = 0u; u2.y = 0u; }
            if (e3 >= n) { u3.x = 0u; u3.y = 0u; }
            if (e0 >= n) { u0.x = 0u; u0.y = 0u; }
            ACC4(u0); ACC4(u1); ACC4(u2); ACC4(u3);
        }
        // merge quarters
        a0 += __shfl_xor(a0, 32, 64); a1 += __shfl_xor(a1, 32, 64);
        a2 += __shfl_xor(a2, 32, 64); a3 += __shfl_xor(a3, 32, 64);
        a0 += __shfl_xor(a0, 16, 64); a1 += __shfl_xor(a1, 16, 64);
        a2 += __shfl_xor(a2, 16, 64); a3 += __shfl_xor(a3, 16, 64);

        float di = dinv[i];
        if (q == 0) {
            ushort4 o;
            o.x = f2bf(fmaxf(di * a0 + bj.x, 0.f));
            o.y = f2bf(fmaxf(di * a1 + bj.y, 0.f));
            o.z = f2bf(fmaxf(di * a2 + bj.z, 0.f));
            o.w = f2bf(fmaxf(di * a3 + bj.w, 0.f));
            *(ushort4*)&hout[i * HID + f4 * 4] = o;
        }
    }
}

// ---------------- gather conv2 fused with scores (round-13) -----------------

__global__ __launch_bounds__(256) void k_gather2s(const unsigned short* __restrict__ mdb,
        const int* __restrict__ prow, const int* __restrict__ bc, const float* __restrict__ dinv,
        const float* __restrict__ b, const float* __restrict__ nw, const float* __restrict__ nb,
        const float* __restrict__ ew, float* __restrict__ out_node,
        float* __restrict__ ssrc, float* __restrict__ sdst) {
    const uint2* mdq = (const uint2*)mdb;
    int lane = threadIdx.x & 63;
    int q    = lane >> 4;
    int f4   = lane & 15;
    int wid  = (blockIdx.x * blockDim.x + threadIdx.x) >> 6;
    int nwv  = (gridDim.x * blockDim.x) >> 6;
    float4 bj  = *(const float4*)&b[f4 * 4];
    float4 wn  = *(const float4*)&nw[f4 * 4];
    float4 we1 = *(const float4*)&ew[f4 * 4];
    float4 we2 = *(const float4*)&ew[64 + f4 * 4];
    float nb0 = nb[0];

    for (int i = wid; i < NN; i += nwv) {
        int vv = bc[i];
        int s = (i >> 7) * CAP + (vv >> 16);
        int n = vv & 0xFFFF;
        float a0 = 0.f, a1 = 0.f, a2 = 0.f, a3 = 0.f;
        if (q == 0) {
            uint2 u = mdq[i * 16 + f4];
            ACC4(u);
        }
        for (int e = 0; e < n; e += 16) {
            int e0 = e + q, e1 = e + 4 + q, e2 = e + 8 + q, e3 = e + 12 + q;
            int r0 = prow[s + (e0 < n ? e0 : 0)];
            int r1 = prow[s + (e1 < n ? e1 : 0)];
            int r2 = prow[s + (e2 < n ? e2 : 0)];
            int r3 = prow[s + (e3 < n ? e3 : 0)];
            uint2 u0 = mdq[r0 * 16 + f4];
            uint2 u1 = mdq[r1 * 16 + f4];
            uint2 u2 = mdq[r2 * 16 + f4];
            uint2 u3 = mdq[r3 * 16 + f4];
            if (e1 >= n) { u1.x = 0u; u1.y = 0u; }
            if (e2 >= n) { u2.x = 0u; u2.y = 0u; }
            if (e3 >= n) { u3.x = 0u; u3.y = 0u; }
            if (e0 >= n) { u0.x = 0u; u0.y = 0u; }
            ACC4(u0); ACC4(u1); ACC4(u2); ACC4(u3);
        }
        a0 += __shfl_xor(a0, 32, 64); a1 += __shfl_xor(a1, 32, 64);
        a2 += __shfl_xor(a2, 32, 64); a3 += __shfl_xor(a3, 32, 64);
        a0 += __shfl_xor(a0, 16, 64); a1 += __shfl_xor(a1, 16, 64);
        a2 += __shfl_xor(a2, 16, 64); a3 += __shfl_xor(a3, 16, 64);

        float di = dinv[i];
        float v0 = fmaxf(di * a0 + bj.x, 0.f);
        float v1 = fmaxf(di * a1 + bj.y, 0.f);
        float v2 = fmaxf(di * a2 + bj.z, 0.f);
        float v3 = fmaxf(di * a3 + bj.w, 0.f);

        float a  = v0 * wn.x  + v1 * wn.y  + v2 * wn.z  + v3 * wn.w;
        float s1 = v0 * we1.x + v1 * we1.y + v2 * we1.z + v3 * we1.w;
        float s2 = v0 * we2.x + v1 * we2.y + v2 * we2.z + v3 * we2.w;
        #pragma unroll
        for (int off = 8; off; off >>= 1) {
            a  += __shfl_xor(a,  off, 64);
            s1 += __shfl_xor(s1, off, 64);
            s2 += __shfl_xor(s2, off, 64);
        }
        if (lane == 0) {
            out_node[i] = 1.f / (1.f + expf(-(a + nb0)));
            ssrc[i] = s1;
            sdst[i] = s2;
        }
    }
}

// ---------------- edge scores (x4 vectorized) -------------------------------

__global__ __launch_bounds__(256) void k_edge(const int4* __restrict__ row4, const int4* __restrict__ col4,
                                              const float* __restrict__ ssrc, const float* __restrict__ sdst,
                                              const float* __restrict__ eb, float4* __restrict__ out4) {
    constexpr int NQ = EE / 4;
    int i = blockIdx.x * 256 + threadIdx.x;
    if (i >= NQ) return;
    float eb0 = eb[0];
    int4 r = row4[i], c = col4[i];
    float4 o;
    float z;
    z = ssrc[r.x] + sdst[c.x] + eb0; o.x = 1.f / (1.f + expf(-z));
    z = ssrc[r.y] + sdst[c.y] + eb0; o.y = 1.f / (1.f + expf(-z));
    z = ssrc[r.z] + sdst[c.z] + eb0; o.z = 1.f / (1.f + expf(-z));
    z = ssrc[r.w] + sdst[c.w] + eb0; o.w = 1.f / (1.f + expf(-z));
    out4[i] = o;
}

extern "C" void kernel_launch(void* const* d_in, const int* in_sizes, int n_in,
                              void* d_out, int out_size, void* d_ws, size_t ws_size,
                              hipStream_t stream) {
    const float* x    = (const float*)d_in[0];
    const int*   ei   = (const int*)d_in[1];
    const float* fc_w = (const float*)d_in[2];
    const float* fc_b = (const float*)d_in[3];
    const float* c1w  = (const float*)d_in[4];
    const float* c1b  = (const float*)d_in[5];
    const float* c2w  = (const float*)d_in[6];
    const float* c2b  = (const float*)d_in[7];
    const float* nw   = (const float*)d_in[8];
    const float* nb   = (const float*)d_in[9];
    const float* ew   = (const float*)d_in[10];
    const float* eb   = (const float*)d_in[11];
    const int* row = ei;        // edge_index[0]
    const int* col = ei + EE;   // edge_index[1]

    // workspace layout (4B units): ~47 MB total
    constexpr int NP = 100352;
    float* ws   = (float*)d_ws;
    float* dinv = ws;                               // NP
    int*   bc   = (int*)(ws + NP);                  // NP
    int*   gcur = (int*)(ws + 2 * NP);              // 1024
    unsigned short* wct = (unsigned short*)(ws + 2 * NP + 1024);  // 8192 bf16 = 4096 f
    float* bvec = ws + 2 * NP + 1024 + 4096;        // 64 (+pad to 128)
    unsigned short* w2t = (unsigned short*)(bvec + 128);          // 4096 bf16 = 2048 f
    int*   ebuf = (int*)(bvec + 128 + 2048);        // NBUCK*CAP
    float* Areg = (float*)(ebuf + NBUCK * CAP);     // h1 region (bf16) / ssrc+sdst
    unsigned short* h1b = (unsigned short*)Areg;    // h1 bf16 [N*HID]
    unsigned short* Bbf = (unsigned short*)(Areg + (size_t)NN * HID / 2);  // md bf16
    float* ssrc = Areg;                             // alias: h1b dead after k_mm2x
    float* sdst = Areg + NP;

    float* out_edge = (float*)d_out;
    float* out_node = out_edge + EE;

    const int nbC = (EE + CHUNK - 1) / CHUNK;   // 391 multisplit chunks
    const int nbQ = (EE / 4 + 255) / 256;       // 1563 edge-quad blocks
    const int nbM = (NTILE + 3) / 4;            // 1563 MFMA blocks (4 waves = 4 tiles)

    // ---- bucketize + in-place node sort (builds CSR + dinv) ----
    k_zero    <<<(NBUCK + 255) / 256, 256, 0, stream>>>(gcur, NBUCK);
    k_bscatter<<<nbC, 256, 0, stream>>>(row, col, gcur, ebuf);
    k_bsortip <<<NBUCK, 256, 0, stream>>>(gcur, ebuf, bc, dinv);

    // ---- weight prep, MFMA transform 1, gather 1 (bf16 h1 out) ----
    k_wc    <<<49, 256, 0, stream>>>(fc_w, fc_b, c1w, c2w, wct, bvec, w2t);
    k_mmx   <<<nbM, 256, 0, stream>>>(x, wct, bvec, dinv, Bbf);
    k_gather<<<2048, 256, 0, stream>>>(Bbf, ebuf, bc, dinv, c1b, h1b);

    // ---- MFMA transform 2, gather 2 fused with scores ----
    k_mm2x    <<<nbM, 256, 0, stream>>>(h1b, w2t, dinv, Bbf);
    k_gather2s<<<2048, 256, 0, stream>>>(Bbf, ebuf, bc, dinv, c2b,
                                         nw, nb, ew, out_node, ssrc, sdst);

    // ---- edge scores ----
    k_edge<<<nbQ, 256, 0, stream>>>((const int4*)row, (const int4*)col,
                                    ssrc, sdst, eb, (float4*)out_edge);
}

// Round 16
// 178.497 us; speedup vs baseline: 1.5960x; 1.0490x over previous
//
#include <hip/hip_runtime.h>
#include <math.h>

// Problem constants (from reference)
constexpr int NN  = 100000;   // nodes (= 6250 * 16, no row tail)
constexpr int EE  = 1600000;  // edges
constexpr int IND = 128;      // input dim
constexpr int HID = 64;       // hidden dim

constexpr int NBUCK = (NN + 127) / 128;   // 782 buckets of 128 nodes
constexpr int CAP   = 2560;               // bucket capacity: 2432 (edge-max, validated r6-15) + 128 selfs
constexpr int CHUNK = 4096;               // edges per multisplit block
constexpr int NTILE = NN / 16;            // 6250 MFMA row-tiles
constexpr int NCB   = (EE + CHUNK - 1) / CHUNK;   // 391 multisplit chunks

using bf16x8 = __attribute__((ext_vector_type(8))) short;
using f32x4v = __attribute__((ext_vector_type(4))) float;

// bf16 helpers (round-to-nearest-even)
__device__ __forceinline__ unsigned short f2bf(float f) {
    union { float f; unsigned int u; } v; v.f = f;
    unsigned int r = (v.u + 0x7FFFu + ((v.u >> 16) & 1u)) >> 16;
    return (unsigned short)r;
}
// unpack a uint holding two bf16 (lo = bits 0..15, hi = bits 16..31)
__device__ __forceinline__ void unp(unsigned int u, float& lo, float& hi) {
    union { unsigned int x; float f; } a, c;
    a.x = u << 16; c.x = u & 0xFFFF0000u;
    lo = a.f; hi = c.f;
}

// accumulate one uint2 (4 bf16) into a0..a3
#define ACC4(u) do { float l_, h_; \
    unp((u).x, l_, h_); a0 += l_; a1 += h_; \
    unp((u).y, l_, h_); a2 += l_; a3 += h_; } while (0)

// ---------------- small zero ----------------

__global__ __launch_bounds__(256) void k_zero(int* __restrict__ p, int n) {
    int i = blockIdx.x * 256 + threadIdx.x;
    if (i < n) p[i] = 0;
}

// ---------------- bucketized multisplit + weight prep (merged) --------------
// Blocks [0, NCB): multisplit with LDS col buffer (single global col read).
// Blocks [NCB, NCB+49): weight prep (Wc^T bf16, bvec, W2^T bf16).

__global__ __launch_bounds__(256) void k_bscatter(const int* __restrict__ row, const int* __restrict__ col,
                                                  int* __restrict__ gcur, int* __restrict__ ebuf,
                                                  const float* __restrict__ wfc, const float* __restrict__ bfc,
                                                  const float* __restrict__ w1, const float* __restrict__ w2,
                                                  unsigned short* __restrict__ wct, float* __restrict__ bvec,
                                                  unsigned short* __restrict__ w2t) {
    __shared__ int lhist[NBUCK];
    __shared__ int lbase[NBUCK];
    __shared__ int lcur[NBUCK];
    __shared__ int lcol[CHUNK];          // 16 KB chunk col buffer
    const int tx = threadIdx.x;

    if (blockIdx.x >= NCB) {             // ---- weight-prep blocks ----
        int b = blockIdx.x - NCB;
        if (b < 32) {
            int idx = b * 256 + tx;      // 0..8191
            int k = idx >> 6, c = idx & 63;
            float acc = 0.f;
            #pragma unroll 8
            for (int j = 0; j < 64; ++j) acc += wfc[k * HID + j] * w1[j * HID + c];
            wct[c * IND + k] = f2bf(acc);        // Wc^T: [c][k]
        } else if (b < 48) {
            int idx = (b - 32) * 256 + tx;       // 0..4095
            int k = idx >> 6, c = idx & 63;
            w2t[c * HID + k] = f2bf(w2[k * HID + c]);
        } else if (tx < 64) {
            float acc = 0.f;
            #pragma unroll 8
            for (int j = 0; j < 64; ++j) acc += bfc[j] * w1[j * HID + tx];
            bvec[tx] = acc;
        }
        return;
    }

    const int cbase = blockIdx.x * CHUNK;

    for (int b = tx; b < NBUCK; b += 256) lhist[b] = 0;
    __syncthreads();

    #pragma unroll
    for (int i = 0; i < CHUNK / 256; ++i) {
        int e = cbase + tx + i * 256;
        int c = (e < EE) ? col[e] : -1;
        lcol[tx + i * 256] = c;
        if (c >= 0) atomicAdd(&lhist[c >> 7], 1);
    }
    __syncthreads();

    for (int b = tx; b < NBUCK; b += 256) {
        int c = lhist[b];
        if (c) lbase[b] = atomicAdd(&gcur[b], c);
        lcur[b] = 0;
    }
    __syncthreads();

    #pragma unroll
    for (int i = 0; i < CHUNK / 256; ++i) {
        int e = cbase + tx + i * 256;
        if (e < EE) {
            int c = lcol[tx + i * 256];
            int b = c >> 7;
            int rank = atomicAdd(&lcur[b], 1);
            ebuf[b * CAP + lbase[b] + rank] = (row[e] << 7) | (c & 127);
        }
    }
}

// ---------------- in-place per-bucket node sort + self-loop fold ------------
// Output entries are BYTE OFFSETS of md rows (row<<7; md row = 64 bf16 =
// 128 B). Each node's segment starts with its own self entry, so the
// gather needs no self special-case. bc[g] = (seg_base<<16) | (deg+1).

__global__ __launch_bounds__(256) void k_bsortip(const int* __restrict__ gcur, int* __restrict__ ebuf,
                                                 int* __restrict__ bc, float* __restrict__ dinv) {
    __shared__ int ebl[CAP];
    __shared__ int h[128];
    __shared__ int sc[128];
    __shared__ int cur[128];
    const int tx = threadIdx.x;
    const int b = blockIdx.x;
    const int cnt = gcur[b];
    int* eb = ebuf + b * CAP;

    if (tx < 128) h[tx] = 0;
    for (int e = tx; e < cnt; e += 256) ebl[e] = eb[e];
    __syncthreads();
    for (int e = tx; e < cnt; e += 256) atomicAdd(&h[ebl[e] & 127], 1);
    __syncthreads();

    // inclusive scan over (h + 1): each node's segment includes its self slot
    if (tx < 128) sc[tx] = h[tx] + 1;
    __syncthreads();
    #pragma unroll
    for (int o = 1; o < 128; o <<= 1) {
        int add = (tx < 128 && tx >= o) ? sc[tx - o] : 0;
        __syncthreads();
        if (tx < 128) sc[tx] += add;
        __syncthreads();
    }
    if (tx < 128) {
        int n1 = h[tx] + 1;
        int ex = sc[tx] - n1;            // segment base (self at ex, edges after)
        cur[tx] = ex + 1;
        int g = b * 128 + tx;
        eb[ex] = g << 7;                 // self entry: byte offset of md row g
        if (g < NN) {
            bc[g]   = (ex << 16) | n1;
            dinv[g] = rsqrtf((float)n1); // deg + self-loop
        }
    }
    __syncthreads();

    for (int e = tx; e < cnt; e += 256) {
        int v = ebl[e];
        int r = atomicAdd(&cur[v & 127], 1);
        eb[r] = v & 0xFFFFFF80;          // row<<7 = byte offset of md row
    }
}

// ---------------- fused fc+conv1 transform via MFMA (round-14 proven) -------

__global__ __launch_bounds__(256) void k_mmx(const float* __restrict__ x,
        const unsigned short* __restrict__ wct, const float* __restrict__ bvec,
        const float* __restrict__ dinv, unsigned short* __restrict__ mdb) {
    const int tx = threadIdx.x;
    const int lane = tx & 63;
    const int wv = tx >> 6;
    const int l15 = lane & 15, g = lane >> 4;
    const int tile = blockIdx.x * 4 + wv;
    if (tile >= NTILE) return;           // no barriers in this kernel
    const int row0 = tile * 16;

    // B fragments: 4 n-tiles x 4 k-chunks (16 KB table, L1/L2-hot)
    bf16x8 bf[4][4];
    #pragma unroll
    for (int t = 0; t < 4; ++t) {
        const unsigned short* bp = wct + (t * 16 + l15) * IND + g * 8;
        #pragma unroll
        for (int kc = 0; kc < 4; ++kc)
            bf[t][kc] = *(const bf16x8*)(bp + kc * 32);
    }

    // A fragments: 8 consecutive f32 of x, converted to bf16 in-register
    const float* ap = x + (row0 + l15) * IND + g * 8;
    bf16x8 af[4];
    #pragma unroll
    for (int kc = 0; kc < 4; ++kc) {
        float4 lo = *(const float4*)(ap + kc * 32);
        float4 hi = *(const float4*)(ap + kc * 32 + 4);
        bf16x8 f;
        f[0] = (short)f2bf(lo.x); f[1] = (short)f2bf(lo.y);
        f[2] = (short)f2bf(lo.z); f[3] = (short)f2bf(lo.w);
        f[4] = (short)f2bf(hi.x); f[5] = (short)f2bf(hi.y);
        f[6] = (short)f2bf(hi.z); f[7] = (short)f2bf(hi.w);
        af[kc] = f;
    }

    // accumulate (bias init: depends only on output col = t*16 + l15)
    f32x4v acc[4];
    #pragma unroll
    for (int t = 0; t < 4; ++t) {
        float bv = bvec[t * 16 + l15];
        acc[t][0] = bv; acc[t][1] = bv; acc[t][2] = bv; acc[t][3] = bv;
    }
    #pragma unroll
    for (int kc = 0; kc < 4; ++kc) {
        #pragma unroll
        for (int t = 0; t < 4; ++t)
            acc[t] = __builtin_amdgcn_mfma_f32_16x16x32_bf16(af[kc], bf[t][kc], acc[t], 0, 0, 0);
    }

    // epilogue: row = row0 + g*4 + r, col = t*16 + l15
    #pragma unroll
    for (int r = 0; r < 4; ++r) {
        int rowg = row0 + g * 4 + r;
        float di = dinv[rowg];
        #pragma unroll
        for (int t = 0; t < 4; ++t)
            mdb[rowg * HID + t * 16 + l15] = f2bf(acc[t][r] * di);
    }
}

// ---------------- conv2 transform via MFMA (round-15 proven) ----------------

__global__ __launch_bounds__(256) void k_mm2x(const unsigned short* __restrict__ h1b,
        const unsigned short* __restrict__ w2t, const float* __restrict__ dinv,
        unsigned short* __restrict__ mdb) {
    const int tx = threadIdx.x;
    const int lane = tx & 63;
    const int wv = tx >> 6;
    const int l15 = lane & 15, g = lane >> 4;
    const int tile = blockIdx.x * 4 + wv;
    if (tile >= NTILE) return;
    const int row0 = tile * 16;

    // B fragments: 4 n-tiles x 2 k-chunks (8 KB table, L1-hot)
    bf16x8 bf[4][2];
    #pragma unroll
    for (int t = 0; t < 4; ++t) {
        const unsigned short* bp = w2t + (t * 16 + l15) * HID + g * 8;
        #pragma unroll
        for (int kc = 0; kc < 2; ++kc)
            bf[t][kc] = *(const bf16x8*)(bp + kc * 32);
    }

    // A fragments: direct bf16 loads of h1 rows
    const unsigned short* ap = h1b + (row0 + l15) * HID + g * 8;
    bf16x8 af[2];
    af[0] = *(const bf16x8*)(ap);
    af[1] = *(const bf16x8*)(ap + 32);

    f32x4v acc[4] = {};
    #pragma unroll
    for (int kc = 0; kc < 2; ++kc) {
        #pragma unroll
        for (int t = 0; t < 4; ++t)
            acc[t] = __builtin_amdgcn_mfma_f32_16x16x32_bf16(af[kc], bf[t][kc], acc[t], 0, 0, 0);
    }

    #pragma unroll
    for (int r = 0; r < 4; ++r) {
        int rowg = row0 + g * 4 + r;
        float di = dinv[rowg];
        #pragma unroll
        for (int t = 0; t < 4; ++t)
            mdb[rowg * HID + t * 16 + l15] = f2bf(acc[t][r] * di);
    }
}

// ---------------- gather conv1 (self folded into segment, byte offsets) -----
// lane = (q=lane>>4 edge slot, f4=lane&15 feature quad). Entries are md-row
// byte offsets -> load address is one add. No self special-case.

__global__ __launch_bounds__(256) void k_gather(const unsigned short* __restrict__ mdb,
                                                const int* __restrict__ ebuf, const int* __restrict__ bc,
                                                const float* __restrict__ dinv, const float* __restrict__ b,
                                                unsigned short* __restrict__ hout) {
    int lane = threadIdx.x & 63;
    int q    = lane >> 4;
    int f4   = lane & 15;
    int wid  = (blockIdx.x * blockDim.x + threadIdx.x) >> 6;
    int nwv  = (gridDim.x * blockDim.x) >> 6;
    float4 bj = *(const float4*)&b[f4 * 4];
    const char* mbase = (const char*)mdb + f4 * 8;

    for (int i = wid; i < NN; i += nwv) {
        int vv = bc[i];
        const int* pr = ebuf + (i >> 7) * CAP + (vv >> 16);
        int n = vv & 0xFFFF;             // includes self (n >= 1)
        float a0 = 0.f, a1 = 0.f, a2 = 0.f, a3 = 0.f;
        for (int e = 0; e < n; e += 16) {
            int e0 = e + q, e1 = e + 4 + q, e2 = e + 8 + q, e3 = e + 12 + q;
            int r0 = pr[e0 < n ? e0 : 0];
            int r1 = pr[e1 < n ? e1 : 0];
            int r2 = pr[e2 < n ? e2 : 0];
            int r3 = pr[e3 < n ? e3 : 0];
            uint2 u0 = *(const uint2*)(mbase + r0);
            uint2 u1 = *(const uint2*)(mbase + r1);
            uint2 u2 = *(const uint2*)(mbase + r2);
            uint2 u3 = *(const uint2*)(mbase + r3);
            if (e0 >= n) { u0.x = 0u; u0.y = 0u; }
            if (e1 >= n) { u1.x = 0u; u1.y = 0u; }
            if (e2 >= n) { u2.x = 0u; u2.y = 0u; }
            if (e3 >= n) { u3.x = 0u; u3.y = 0u; }
            ACC4(u0); ACC4(u1); ACC4(u2); ACC4(u3);
        }
        // merge quarters
        a0 += __shfl_xor(a0, 32, 64); a1 += __shfl_xor(a1, 32, 64);
        a2 += __shfl_xor(a2, 32, 64); a3 += __shfl_xor(a3, 32, 64);
        a0 += __shfl_xor(a0, 16, 64); a1 += __shfl_xor(a1, 16, 64);
        a2 += __shfl_xor(a2, 16, 64); a3 += __shfl_xor(a3, 16, 64);

        if (q == 0) {
            float di = dinv[i];
            ushort4 o;
            o.x = f2bf(fmaxf(di * a0 + bj.x, 0.f));
            o.y = f2bf(fmaxf(di * a1 + bj.y, 0.f));
            o.z = f2bf(fmaxf(di * a2 + bj.z, 0.f));
            o.w = f2bf(fmaxf(di * a3 + bj.w, 0.f));
            *(ushort4*)&hout[i * HID + f4 * 4] = o;
        }
    }
}

// ---------------- gather conv2 fused with scores (same restructure) ---------

__global__ __launch_bounds__(256) void k_gather2s(const unsigned short* __restrict__ mdb,
        const int* __restrict__ ebuf, const int* __restrict__ bc, const float* __restrict__ dinv,
        const float* __restrict__ b, const float* __restrict__ nw, const float* __restrict__ nb,
        const float* __restrict__ ew, float* __restrict__ out_node,
        float* __restrict__ ssrc, float* __restrict__ sdst) {
    int lane = threadIdx.x & 63;
    int q    = lane >> 4;
    int f4   = lane & 15;
    int wid  = (blockIdx.x * blockDim.x + threadIdx.x) >> 6;
    int nwv  = (gridDim.x * blockDim.x) >> 6;
    float4 bj  = *(const float4*)&b[f4 * 4];
    float4 wn  = *(const float4*)&nw[f4 * 4];
    float4 we1 = *(const float4*)&ew[f4 * 4];
    float4 we2 = *(const float4*)&ew[64 + f4 * 4];
    float nb0 = nb[0];
    const char* mbase = (const char*)mdb + f4 * 8;

    for (int i = wid; i < NN; i += nwv) {
        int vv = bc[i];
        const int* pr = ebuf + (i >> 7) * CAP + (vv >> 16);
        int n = vv & 0xFFFF;
        float a0 = 0.f, a1 = 0.f, a2 = 0.f, a3 = 0.f;
        for (int e = 0; e < n; e += 16) {
            int e0 = e + q, e1 = e + 4 + q, e2 = e + 8 + q, e3 = e + 12 + q;
            int r0 = pr[e0 < n ? e0 : 0];
            int r1 = pr[e1 < n ? e1 : 0];
            int r2 = pr[e2 < n ? e2 : 0];
            int r3 = pr[e3 < n ? e3 : 0];
            uint2 u0 = *(const uint2*)(mbase + r0);
            uint2 u1 = *(const uint2*)(mbase + r1);
            uint2 u2 = *(const uint2*)(mbase + r2);
            uint2 u3 = *(const uint2*)(mbase + r3);
            if (e0 >= n) { u0.x = 0u; u0.y = 0u; }
            if (e1 >= n) { u1.x = 0u; u1.y = 0u; }
            if (e2 >= n) { u2.x = 0u; u2.y = 0u; }
            if (e3 >= n) { u3.x = 0u; u3.y = 0u; }
            ACC4(u0); ACC4(u1); ACC4(u2); ACC4(u3);
        }
        a0 += __shfl_xor(a0, 32, 64); a1 += __shfl_xor(a1, 32, 64);
        a2 += __shfl_xor(a2, 32, 64); a3 += __shfl_xor(a3, 32, 64);
        a0 += __shfl_xor(a0, 16, 64); a1 += __shfl_xor(a1, 16, 64);
        a2 += __shfl_xor(a2, 16, 64); a3 += __shfl_xor(a3, 16, 64);

        float di = dinv[i];
        float v0 = fmaxf(di * a0 + bj.x, 0.f);
        float v1 = fmaxf(di * a1 + bj.y, 0.f);
        float v2 = fmaxf(di * a2 + bj.z, 0.f);
        float v3 = fmaxf(di * a3 + bj.w, 0.f);

        float a  = v0 * wn.x  + v1 * wn.y  + v2 * wn.z  + v3 * wn.w;
        float s1 = v0 * we1.x + v1 * we1.y + v2 * we1.z + v3 * we1.w;
        float s2 = v0 * we2.x + v1 * we2.y + v2 * we2.z + v3 * we2.w;
        #pragma unroll
        for (int off = 8; off; off >>= 1) {
            a  += __shfl_xor(a,  off, 64);
            s1 += __shfl_xor(s1, off, 64);
            s2 += __shfl_xor(s2, off, 64);
        }
        if (lane == 0) {
            out_node[i] = 1.f / (1.f + expf(-(a + nb0)));
            ssrc[i] = s1;
            sdst[i] = s2;
        }
    }
}

// ---------------- edge scores (x4 vectorized) -------------------------------

__global__ __launch_bounds__(256) void k_edge(const int4* __restrict__ row4, const int4* __restrict__ col4,
                                              const float* __restrict__ ssrc, const float* __restrict__ sdst,
                                              const float* __restrict__ eb, float4* __restrict__ out4) {
    constexpr int NQ = EE / 4;
    int i = blockIdx.x * 256 + threadIdx.x;
    if (i >= NQ) return;
    float eb0 = eb[0];
    int4 r = row4[i], c = col4[i];
    float4 o;
    float z;
    z = ssrc[r.x] + sdst[c.x] + eb0; o.x = 1.f / (1.f + expf(-z));
    z = ssrc[r.y] + sdst[c.y] + eb0; o.y = 1.f / (1.f + expf(-z));
    z = ssrc[r.z] + sdst[c.z] + eb0; o.z = 1.f / (1.f + expf(-z));
    z = ssrc[r.w] + sdst[c.w] + eb0; o.w = 1.f / (1.f + expf(-z));
    out4[i] = o;
}

extern "C" void kernel_launch(void* const* d_in, const int* in_sizes, int n_in,
                              void* d_out, int out_size, void* d_ws, size_t ws_size,
                              hipStream_t stream) {
    const float* x    = (const float*)d_in[0];
    const int*   ei   = (const int*)d_in[1];
    const float* fc_w = (const float*)d_in[2];
    const float* fc_b = (const float*)d_in[3];
    const float* c1w  = (const float*)d_in[4];
    const float* c1b  = (const float*)d_in[5];
    const float* c2w  = (const float*)d_in[6];
    const float* c2b  = (const float*)d_in[7];
    const float* nw   = (const float*)d_in[8];
    const float* nb   = (const float*)d_in[9];
    const float* ew   = (const float*)d_in[10];
    const float* eb   = (const float*)d_in[11];
    const int* row = ei;        // edge_index[0]
    const int* col = ei + EE;   // edge_index[1]

    // workspace layout (4B units): ~35 MB total
    constexpr int NP = 100352;
    float* ws   = (float*)d_ws;
    float* dinv = ws;                               // NP
    int*   bc   = (int*)(ws + NP);                  // NP
    int*   gcur = (int*)(ws + 2 * NP);              // 1024
    unsigned short* wct = (unsigned short*)(ws + 2 * NP + 1024);  // 8192 bf16 = 4096 f
    float* bvec = ws + 2 * NP + 1024 + 4096;        // 64 (+pad to 128)
    unsigned short* w2t = (unsigned short*)(bvec + 128);          // 4096 bf16 = 2048 f
    int*   ebuf = (int*)(bvec + 128 + 2048);        // NBUCK*CAP
    float* Areg = (float*)(ebuf + NBUCK * CAP);     // h1 (bf16) / ssrc+sdst
    unsigned short* h1b = (unsigned short*)Areg;    // h1 bf16 [N*HID]
    unsigned short* Bbf = (unsigned short*)(Areg + (size_t)NN * HID / 2);  // md bf16
    float* ssrc = Areg;                             // alias: h1b dead after k_mm2x
    float* sdst = Areg + NP;

    float* out_edge = (float*)d_out;
    float* out_node = out_edge + EE;

    const int nbQ = (EE / 4 + 255) / 256;       // 1563 edge-quad blocks
    const int nbM = (NTILE + 3) / 4;            // 1563 MFMA blocks (4 waves = 4 tiles)

    // ---- bucketize (+ weight prep merged) + in-place node sort ----
    k_zero    <<<(NBUCK + 255) / 256, 256, 0, stream>>>(gcur, NBUCK);
    k_bscatter<<<NCB + 49, 256, 0, stream>>>(row, col, gcur, ebuf,
                                             fc_w, fc_b, c1w, c2w, wct, bvec, w2t);
    k_bsortip <<<NBUCK, 256, 0, stream>>>(gcur, ebuf, bc, dinv);

    // ---- MFMA transform 1, gather 1 (bf16 h1 out) ----
    k_mmx   <<<nbM, 256, 0, stream>>>(x, wct, bvec, dinv, Bbf);
    k_gather<<<2048, 256, 0, stream>>>(Bbf, ebuf, bc, dinv, c1b, h1b);

    // ---- MFMA transform 2, gather 2 fused with scores ----
    k_mm2x    <<<nbM, 256, 0, stream>>>(h1b, w2t, dinv, Bbf);
    k_gather2s<<<2048, 256, 0, stream>>>(Bbf, ebuf, bc, dinv, c2b,
                                         nw, nb, ew, out_node, ssrc, sdst);

    // ---- edge scores ----
    k_edge<<<nbQ, 256, 0, stream>>>((const int4*)row, (const int4*)col,
                                    ssrc, sdst, eb, (float4*)out_edge);
}